// Round 10
// baseline (10309.914 us; speedup 1.0000x reference)
//
#include <hip/hip_runtime.h>
#include <math.h>

// IDE state-space Kalman filter, MI355X (gfx950). Round 17:
// R16 (8354 us) + 1-barrier-per-panel RIGHT-LOOKING chol (14 -> 7 phases;
// 20 -> 13 barriers/step). Invariant at phase kb: tiles bj>=kb hold panels
// 0..kb-2; diag kb factorized. Roles per phase (single barrier):
//  - TRSM crew (w1-2): rows>=16(kb+2): inline panel-(kb-1) correction (fp32,
//    reads only phase-(kb-1) data) -> substitution -> fp32 + Lhi/Llo.
//  - wave0: block (kb+1,kb) same; diag kb+1 -= panels {kb-1 (LDS), kb (regs)}
//    via ONE 3-MFMA set: 32-wide K = [panel kb-1 | panel kb], quads 0-1 from
//    Lhi/Llo, quads 2-3 packed from registers (zero-pad in REGISTERS -> no
//    LDS zero stores, no races, no new builtins) -> chol16(kb+1).
//  - MFMA crew (w3-15): panel kb-1 -> tiles bj>=kb+1 (excl diag kb+1),
//    3 MFMAs/tile, K=16 via register-zeroed upper. Write sets disjoint.
// Micro: MC y-GEMV 4-way accumulators; Pn GEMV 2-way.

#define SQ 64
#define DQ 128
#define TQ 128
#define BQ 16
#define LDP 132           // fp32 row stride
#define LDB 136           // bf16 row stride (16B-aligned rows, 2-way banks)
#define WFLOATS 17408     // W region: 69632 B (Tb + Ab2 bf16 when dead)
#define NTH 1024
#define LOG2PI 1.8378770664093454f

#define SMEM_FLOATS 35472

typedef __attribute__((ext_vector_type(8))) short bf16x8;
typedef __attribute__((ext_vector_type(4))) float f32x4;

__device__ __forceinline__ void lds_fence() {
  __asm__ volatile("s_waitcnt lgkmcnt(0)" ::: "memory");
}

__device__ __forceinline__ unsigned short f2bf(float f) {
  unsigned u = __float_as_uint(f);
  u += 0x7fffu + ((u >> 16) & 1u);
  return (unsigned short)(u >> 16);
}
__device__ __forceinline__ uint4 pack8(const float* v) {
  uint4 r;
  r.x = (unsigned)f2bf(v[0]) | ((unsigned)f2bf(v[1]) << 16);
  r.y = (unsigned)f2bf(v[2]) | ((unsigned)f2bf(v[3]) << 16);
  r.z = (unsigned)f2bf(v[4]) | ((unsigned)f2bf(v[5]) << 16);
  r.w = (unsigned)f2bf(v[6]) | ((unsigned)f2bf(v[7]) << 16);
  return r;
}

__device__ __forceinline__ float block_reduce_sum(float v, float* red) {
  #pragma unroll
  for (int off = 32; off > 0; off >>= 1) v += __shfl_down(v, off);
  const int tid = threadIdx.x;
  if ((tid & 63) == 0) red[tid >> 6] = v;
  __syncthreads();
  v = 0.0f;
  #pragma unroll
  for (int w = 0; w < NTH / 64; w++) v += red[w];
  __syncthreads();
  return v;
}

// 16x16 Cholesky, factor only (register/shfl resident on one wave).
__device__ __forceinline__ void chol16_f(float* __restrict__ Wf,
                                         float* __restrict__ mdiag,
                                         int b0, int lane) {
  float a[16];
  if (lane < 16) {
    const float4* rp = (const float4*)(Wf + (b0 + lane) * LDP + b0);
    float4 q0 = rp[0], q1 = rp[1], q2v = rp[2], q3 = rp[3];
    a[0]=q0.x; a[1]=q0.y; a[2]=q0.z; a[3]=q0.w;
    a[4]=q1.x; a[5]=q1.y; a[6]=q1.z; a[7]=q1.w;
    a[8]=q2v.x; a[9]=q2v.y; a[10]=q2v.z; a[11]=q2v.w;
    a[12]=q3.x; a[13]=q3.y; a[14]=q3.z; a[15]=q3.w;
  } else {
    #pragma unroll
    for (int i = 0; i < 16; i++) a[i] = 1.0f;
  }
  float myrinv = 1.0f;
  #pragma unroll
  for (int j = 0; j < 16; j++) {
    float dj = __shfl(a[j], j);
    float rinv = rsqrtf(dj);
    float lij = a[j] * rinv;
    a[j] = lij;
    if (lane == j) myrinv = rinv;
    #pragma unroll
    for (int k = j + 1; k < 16; k++) {
      float lkj = __shfl(lij, k);
      a[k] = fmaf(-lij, lkj, a[k]);
    }
  }
  if (lane < 16) {
    float4* rp = (float4*)(Wf + (b0 + lane) * LDP + b0);
    rp[0] = make_float4(a[0], a[1], a[2], a[3]);
    rp[1] = make_float4(a[4], a[5], a[6], a[7]);
    rp[2] = make_float4(a[8], a[9], a[10], a[11]);
    rp[3] = make_float4(a[12], a[13], a[14], a[15]);
    mdiag[b0 + lane] = myrinv;
  }
}

// One trinv chain: columns {4g+pass} of M(*,J) (see R13 notes).
__device__ __forceinline__ void trinv_chain2(float* __restrict__ Wf,
                                             const float* __restrict__ mdiag,
                                             int J, int pass, int lane) {
  const int c16 = lane & 15;
  const int j16 = 4 * (lane >> 4) + pass;
  const int sh = lane & 48;
  // ---- step 1: column j16 of Linv_J ----
  {
    float row[16];
    const float4* rp = (const float4*)(Wf + (J * 16 + c16) * LDP + J * 16);
    float4 a0 = rp[0], a1 = rp[1], a2 = rp[2], a3 = rp[3];
    row[0]=a0.x; row[1]=a0.y; row[2]=a0.z; row[3]=a0.w;
    row[4]=a1.x; row[5]=a1.y; row[6]=a1.z; row[7]=a1.w;
    row[8]=a2.x; row[9]=a2.y; row[10]=a2.z; row[11]=a2.w;
    row[12]=a3.x; row[13]=a3.y; row[14]=a3.z; row[15]=a3.w;
    float s = (c16 == j16) ? 1.0f : 0.0f;
    #pragma unroll
    for (int k = 0; k < 16; k++) {
      if (c16 == k) s *= mdiag[J * 16 + k];
      float sk = __shfl(s, sh | k);
      if (c16 > k) s = fmaf(-row[k], sk, s);
    }
    if (c16 > j16) Wf[(J * 16 + j16) * LDP + (J * 16 + c16)] = s;
  }
  lds_fence();
  const float md = mdiag[J * 16 + j16];
  const float* Mrow = Wf + (J * 16 + j16) * LDP + J * 16;
  #pragma unroll 1
  for (int I = J + 1; I < 8; I++) {
    const float* Lrow = Wf + (I * 16 + c16) * LDP + J * 16;
    float g = 0.0f;
    #pragma unroll
    for (int c4 = 0; c4 < 4; c4++) {
      float4 lv = *(const float4*)&Lrow[c4 * 4];
      float4 mq = *(const float4*)&Mrow[c4 * 4];
      float w0 = (c4*4+0 > j16) ? mq.x : ((c4*4+0 == j16) ? md : 0.0f);
      float w1 = (c4*4+1 > j16) ? mq.y : ((c4*4+1 == j16) ? md : 0.0f);
      float w2 = (c4*4+2 > j16) ? mq.z : ((c4*4+2 == j16) ? md : 0.0f);
      float w3 = (c4*4+3 > j16) ? mq.w : ((c4*4+3 == j16) ? md : 0.0f);
      g = fmaf(lv.x, w0, g); g = fmaf(lv.y, w1, g);
      g = fmaf(lv.z, w2, g); g = fmaf(lv.w, w3, g);
    }
    for (int K = J + 1; K < I; K++) {
      const float* LK = Lrow + (K - J) * 16;
      const float* MK = Wf + (J * 16 + j16) * LDP + K * 16;
      #pragma unroll
      for (int c4 = 0; c4 < 4; c4++) {
        float4 lv = *(const float4*)&LK[c4 * 4];
        float4 mq = *(const float4*)&MK[c4 * 4];
        g = fmaf(lv.x, mq.x, g); g = fmaf(lv.y, mq.y, g);
        g = fmaf(lv.z, mq.z, g); g = fmaf(lv.w, mq.w, g);
      }
    }
    float row2[16];
    {
      const float4* rp2 = (const float4*)(Wf + (I * 16 + c16) * LDP + I * 16);
      float4 a0 = rp2[0], a1 = rp2[1], a2 = rp2[2], a3 = rp2[3];
      row2[0]=a0.x; row2[1]=a0.y; row2[2]=a0.z; row2[3]=a0.w;
      row2[4]=a1.x; row2[5]=a1.y; row2[6]=a1.z; row2[7]=a1.w;
      row2[8]=a2.x; row2[9]=a2.y; row2[10]=a2.z; row2[11]=a2.w;
      row2[12]=a3.x; row2[13]=a3.y; row2[14]=a3.z; row2[15]=a3.w;
    }
    float sv = g;
    #pragma unroll
    for (int k = 0; k < 16; k++) {
      if (c16 == k) sv *= mdiag[I * 16 + k];
      float sk = __shfl(sv, sh | k);
      if (c16 > k) sv = fmaf(-row2[k], sk, sv);
    }
    Wf[(J * 16 + j16) * LDP + (I * 16 + c16)] = -sv;
    lds_fence();
  }
}

extern "C" __global__ __launch_bounds__(NTH, 4)
void ide_kf_kernel(const float* __restrict__ z_seq,
                   const float* __restrict__ site_lon,
                   const float* __restrict__ site_lat,
                   const float* __restrict__ mu_seq,
                   const float* __restrict__ sigma_seq,
                   const float* __restrict__ log_q,
                   const float* __restrict__ log_r,
                   const float* __restrict__ log_p0,
                   const float* __restrict__ log_damp,
                   const float* __restrict__ init_mean,
                   const float* __restrict__ coupling_raw,
                   float* __restrict__ ws) {
  extern __shared__ float smem[];
  float* Wf     = smem;                  // 17408 floats (fp32 chol space)
  float* B1f    = Wf + WFLOATS;          // 8704 floats (Mtb bf16 / Lhi)
  float* B2f    = B1f + 8704;            // 8704 floats (Pb bf16 / Llo)
  float* coords = B2f + 8704;            // 128
  float* mv     = coords + 128;          // 128 (posterior mean)
  float* vv     = mv + DQ;               // 128
  float* yv     = vv + DQ;               // 128
  float* mdiag  = yv + DQ;               // 128
  float* red    = mdiag + DQ;            // 16

  unsigned short* Tb  = (unsigned short*)Wf;            // bf16, stride LDB
  unsigned short* Ab2 = (unsigned short*)Wf + 17408;    // A bf16 (Wf upper)
  unsigned short* Mtb = (unsigned short*)B1f;           // M^T bf16
  unsigned short* Pb  = (unsigned short*)B2f;           // P bf16 (symmetric)
  unsigned short* Lhi = (unsigned short*)B1f;           // chol L hi (Mtb dead)
  unsigned short* Llo = (unsigned short*)B2f;           // chol L lo (Pb dead)

  const int tid = threadIdx.x;
  const int lane = tid & 63;
  const int wave = tid >> 6;
  const int rb = wave >> 1, ch = wave & 1;
  const int m16 = lane & 15, quad = lane >> 4;
  const int grp = wave >> 2, pass = wave & 3;
  const int b = blockIdx.x;
  float* nll_out = ws;

  const float r2 = __expf(2.0f * log_r[0]);
  const float q2 = __expf(2.0f * log_q[0]);
  const float p0sq = __expf(2.0f * log_p0[0]);
  const float damping = __expf(log_damp[0]);
  const float cpl00 = 1.0f + 0.25f * tanhf(coupling_raw[0]);
  const float cpl01 = 0.25f * tanhf(coupling_raw[1]);
  const float cpl10 = 0.25f * tanhf(coupling_raw[2]);
  const float cpl11 = 1.0f + 0.25f * tanhf(coupling_raw[3]);

  // ---- lon/lat projection ----
  float myLon = (tid < SQ) ? site_lon[tid] : 0.0f;
  float myLat = (tid < SQ) ? site_lat[tid] : 0.0f;
  float lat0 = block_reduce_sum(myLat, red) * (1.0f / 64.0f);
  float lon0 = block_reduce_sum(myLon, red) * (1.0f / 64.0f);
  if (tid < SQ) {
    const float km = 111.32f;
    float cs = cosf(lat0 * 0.017453292519943295f);
    coords[2 * tid]     = (myLon - lon0) * (km * cs);
    coords[2 * tid + 1] = (myLat - lat0) * km;
  }
  __syncthreads();
  float dsum = 0.0f, dcnt = 0.0f;
  for (int idx = tid; idx < SQ * SQ; idx += NTH) {
    int i = idx >> 6, j = idx & 63;
    float dx = coords[2 * i] - coords[2 * j];
    float dy = coords[2 * i + 1] - coords[2 * j + 1];
    float d = sqrtf(dx * dx + dy * dy + 1e-12f);
    dsum += d;
    if (d > 1e-6f) dcnt += 1.0f;
  }
  dsum = block_reduce_sum(dsum, red);
  dcnt = block_reduce_sum(dcnt, red);
  float scale = dsum / fmaxf(dcnt, 1.0f);
  float sdiv = 1.0f / fmaxf(scale, 1e-6f);
  if (tid < SQ) { coords[2 * tid] *= sdiv; coords[2 * tid + 1] *= sdiv; }

  // ---- init: Wf = (p0sq+r2) I, mv = init_mean ----
  for (int e = tid; e < WFLOATS / 4; e += NTH)
    ((float4*)Wf)[e] = make_float4(0.0f, 0.0f, 0.0f, 0.0f);
  for (int e = tid; e < 8704 / 4; e += NTH)
    ((float4*)B2f)[e] = make_float4(0.0f, 0.0f, 0.0f, 0.0f);
  __syncthreads();
  if (tid < DQ) {
    Wf[tid * LDP + tid] = p0sq + r2;
    mv[tid] = init_mean[tid];
  }
  __syncthreads();

  float nllp = 0.0f;

  #pragma unroll 1
  for (int t = 0; t < TQ; t++) {
    const float* zt = z_seq + ((size_t)b * TQ + t) * DQ;

    if (t > 0) {
      // ---- PHASE T: mfma T = A*P -> Tb (single barrier) ----
      {
        f32x4 acc[4];
        #pragma unroll
        for (int c = 0; c < 4; c++) acc[c] = (f32x4){0.0f, 0.0f, 0.0f, 0.0f};
        #pragma unroll
        for (int ks = 0; ks < 4; ks++) {
          const int ko = 32 * ks + 8 * quad;
          bf16x8 a = *(const bf16x8*)(Ab2 + (16 * rb + m16) * LDB + ko);
          #pragma unroll
          for (int ct = 0; ct < 4; ct++) {
            bf16x8 bb = *(const bf16x8*)(Pb + (64 * ch + 16 * ct + m16) * LDB + ko);
            acc[ct] = __builtin_amdgcn_mfma_f32_16x16x32_bf16(a, bb, acc[ct], 0, 0, 0);
          }
        }
        #pragma unroll
        for (int ct = 0; ct < 4; ct++)
          #pragma unroll
          for (int reg = 0; reg < 4; reg++)
            Tb[(16 * rb + 4 * quad + reg) * LDB + 64 * ch + 16 * ct + m16] =
                f2bf(acc[ct][reg]);
        __syncthreads();
      }

      // ---- PHASE P': part1: Sm MFMA + m-GEMV (idle waves 1,3);
      //      midbar; part2: fp32 Wf + wave0 chol16_f(0) + vv ----
      {
        const int ctmax = rb - 4 * ch;
        f32x4 acc[4];
        #pragma unroll
        for (int c = 0; c < 4; c++) acc[c] = (f32x4){0.0f, 0.0f, 0.0f, 0.0f};
        const bool gemv_wave = (wave == 1 || wave == 3);
        const int grow = (wave == 1) ? lane : 64 + lane;
        float newm = 0.0f;
        if (ctmax >= 0) {
          #pragma unroll
          for (int ks = 0; ks < 4; ks++) {
            const int ko = 32 * ks + 8 * quad;
            bf16x8 a = *(const bf16x8*)(Tb + (16 * rb + m16) * LDB + ko);
            #pragma unroll
            for (int ct = 0; ct < 4; ct++) {
              if (ct <= ctmax) {
                bf16x8 bb = *(const bf16x8*)(Ab2 + (64 * ch + 16 * ct + m16) * LDB + ko);
                acc[ct] = __builtin_amdgcn_mfma_f32_16x16x32_bf16(a, bb, acc[ct], 0, 0, 0);
              }
            }
          }
        } else if (gemv_wave) {
          const unsigned* ar = (const unsigned*)(Ab2 + grow * LDB);
          #pragma unroll 8
          for (int k2 = 0; k2 < 64; k2++) {
            unsigned p = ar[k2];
            newm = fmaf(__uint_as_float(p << 16), mv[2 * k2], newm);
            newm = fmaf(__uint_as_float(p & 0xffff0000u), mv[2 * k2 + 1], newm);
          }
        }
        __syncthreads();   // Tb/Ab2 reads done
        if (ctmax >= 0) {
          #pragma unroll
          for (int ct = 0; ct < 4; ct++) {
            if (ct <= ctmax) {
              #pragma unroll
              for (int reg = 0; reg < 4; reg++) {
                const int rg = 16 * rb + 4 * quad + reg;
                const int cgl = 64 * ch + 16 * ct + m16;
                Wf[rg * LDP + cgl] = acc[ct][reg] + ((rg == cgl) ? (q2 + r2) : 0.0f);
              }
            }
          }
        }
        if (gemv_wave) vv[grow] = zt[grow] - newm;
        if (wave == 0) {
          lds_fence();
          chol16_f(Wf, mdiag, 0, lane);
        }
        __syncthreads();
      }
    }

    if (t == 0) {
      // ---- K0 (t=0 only): wave0 chol diag0 ; vv ----
      if (tid < 64) {
        chol16_f(Wf, mdiag, 0, lane);
      } else if (tid < 192) {
        const int i = tid - 64;
        vv[i] = zt[i] - mv[i];
      }
      __syncthreads();
    }

    // ---- chol: right-looking one-panel-lag, ONE barrier per panel ----
    #pragma unroll 1
    for (int kb = 0; kb < 7; kb++) {
      const int b0k = kb * 16, base = b0k + 16, bm1 = b0k - 16;
      if (wave == 0) {
        // block (kb+1,kb): correction + TRSM + diag(kb+1) MFMA + chol16.
        const int r16 = m16, q4 = quad;
        const int r = base + r16;
        float w[16];
        {
          const float4* rp = (const float4*)(Wf + r * LDP + b0k);
          float4 a0 = rp[0], a1 = rp[1], a2 = rp[2], a3 = rp[3];
          w[0]=a0.x; w[1]=a0.y; w[2]=a0.z; w[3]=a0.w;
          w[4]=a1.x; w[5]=a1.y; w[6]=a1.z; w[7]=a1.w;
          w[8]=a2.x; w[9]=a2.y; w[10]=a2.z; w[11]=a2.w;
          w[12]=a3.x; w[13]=a3.y; w[14]=a3.z; w[15]=a3.w;
        }
        if (kb > 0) {
          float lp[16];
          const float4* rp = (const float4*)(Wf + r * LDP + bm1);
          float4 a0 = rp[0], a1 = rp[1], a2 = rp[2], a3 = rp[3];
          lp[0]=a0.x; lp[1]=a0.y; lp[2]=a0.z; lp[3]=a0.w;
          lp[4]=a1.x; lp[5]=a1.y; lp[6]=a1.z; lp[7]=a1.w;
          lp[8]=a2.x; lp[9]=a2.y; lp[10]=a2.z; lp[11]=a2.w;
          lp[12]=a3.x; lp[13]=a3.y; lp[14]=a3.z; lp[15]=a3.w;
          #pragma unroll
          for (int c = 0; c < 16; c++) {
            const float* Lb = Wf + (b0k + c) * LDP + bm1;
            float s = 0.0f;
            #pragma unroll
            for (int c4 = 0; c4 < 4; c4++) {
              float4 lv = *(const float4*)&Lb[c4 * 4];
              s = fmaf(lp[c4*4+0], lv.x, s);
              s = fmaf(lp[c4*4+1], lv.y, s);
              s = fmaf(lp[c4*4+2], lv.z, s);
              s = fmaf(lp[c4*4+3], lv.w, s);
            }
            w[c] -= s;
          }
        }
        #pragma unroll
        for (int j = 0; j < 16; j++) {
          float s = w[j];
          const float* Ld = Wf + (b0k + j) * LDP + b0k;
          #pragma unroll
          for (int l = 0; l < 16; l++) {
            if (l < j) s = fmaf(-w[l], Ld[l], s);
          }
          w[j] = s * mdiag[b0k + j];
        }
        if (q4 == 0) {
          float4* wp = (float4*)(Wf + r * LDP + b0k);
          wp[0] = make_float4(w[0], w[1], w[2], w[3]);
          wp[1] = make_float4(w[4], w[5], w[6], w[7]);
          wp[2] = make_float4(w[8], w[9], w[10], w[11]);
          wp[3] = make_float4(w[12], w[13], w[14], w[15]);
          unsigned short hs[16]; float lo[16];
          #pragma unroll
          for (int u = 0; u < 16; u++) {
            hs[u] = f2bf(w[u]);
            lo[u] = w[u] - __uint_as_float(((unsigned)hs[u]) << 16);
          }
          uint4 h0, h1;
          h0.x = hs[0] | ((unsigned)hs[1] << 16);   h0.y = hs[2] | ((unsigned)hs[3] << 16);
          h0.z = hs[4] | ((unsigned)hs[5] << 16);   h0.w = hs[6] | ((unsigned)hs[7] << 16);
          h1.x = hs[8] | ((unsigned)hs[9] << 16);   h1.y = hs[10] | ((unsigned)hs[11] << 16);
          h1.z = hs[12] | ((unsigned)hs[13] << 16); h1.w = hs[14] | ((unsigned)hs[15] << 16);
          unsigned short* hr = Lhi + r * LDB + b0k;
          unsigned short* lr = Llo + r * LDB + b0k;
          *(uint4*)(hr) = h0; *(uint4*)(hr + 8) = h1;
          *(uint4*)(lr) = pack8(lo); *(uint4*)(lr + 8) = pack8(lo + 8);
        }
        // diag (kb+1): 3-MFMA over K = [panel kb-1 | panel kb].
        bf16x8 ahi = {0,0,0,0,0,0,0,0}, alo = {0,0,0,0,0,0,0,0};
        if (q4 < 2) {
          if (kb > 0) {
            const int ko = bm1 + 8 * q4;
            ahi = *(const bf16x8*)(Lhi + r * LDB + ko);
            alo = *(const bf16x8*)(Llo + r * LDB + ko);
          }
        } else if (q4 == 2) {
          #pragma unroll
          for (int u = 0; u < 8; u++) {
            unsigned short h = f2bf(w[u]);
            ahi[u] = (short)h;
            alo[u] = (short)f2bf(w[u] - __uint_as_float(((unsigned)h) << 16));
          }
        } else {
          #pragma unroll
          for (int u = 0; u < 8; u++) {
            unsigned short h = f2bf(w[8 + u]);
            ahi[u] = (short)h;
            alo[u] = (short)f2bf(w[8 + u] - __uint_as_float(((unsigned)h) << 16));
          }
        }
        f32x4 acc = (f32x4){0.0f, 0.0f, 0.0f, 0.0f};
        acc = __builtin_amdgcn_mfma_f32_16x16x32_bf16(ahi, ahi, acc, 0, 0, 0);
        acc = __builtin_amdgcn_mfma_f32_16x16x32_bf16(ahi, alo, acc, 0, 0, 0);
        acc = __builtin_amdgcn_mfma_f32_16x16x32_bf16(alo, ahi, acc, 0, 0, 0);
        #pragma unroll
        for (int reg = 0; reg < 4; reg++)
          Wf[(base + 4 * q4 + reg) * LDP + base + m16] -= acc[reg];
        lds_fence();
        chol16_f(Wf, mdiag, base, lane);
      } else if (wave <= 2) {
        // TRSM crew: rows 16(kb+2)..127.
        const int rr = tid - 64;
        const int nrows = 96 - 16 * kb;
        if (rr < nrows) {
          const int r = 16 * (kb + 2) + rr;
          float w[16];
          {
            const float4* rp = (const float4*)(Wf + r * LDP + b0k);
            float4 a0 = rp[0], a1 = rp[1], a2 = rp[2], a3 = rp[3];
            w[0]=a0.x; w[1]=a0.y; w[2]=a0.z; w[3]=a0.w;
            w[4]=a1.x; w[5]=a1.y; w[6]=a1.z; w[7]=a1.w;
            w[8]=a2.x; w[9]=a2.y; w[10]=a2.z; w[11]=a2.w;
            w[12]=a3.x; w[13]=a3.y; w[14]=a3.z; w[15]=a3.w;
          }
          if (kb > 0) {
            float lp[16];
            const float4* rp = (const float4*)(Wf + r * LDP + bm1);
            float4 a0 = rp[0], a1 = rp[1], a2 = rp[2], a3 = rp[3];
            lp[0]=a0.x; lp[1]=a0.y; lp[2]=a0.z; lp[3]=a0.w;
            lp[4]=a1.x; lp[5]=a1.y; lp[6]=a1.z; lp[7]=a1.w;
            lp[8]=a2.x; lp[9]=a2.y; lp[10]=a2.z; lp[11]=a2.w;
            lp[12]=a3.x; lp[13]=a3.y; lp[14]=a3.z; lp[15]=a3.w;
            #pragma unroll
            for (int c = 0; c < 16; c++) {
              const float* Lb = Wf + (b0k + c) * LDP + bm1;
              float s = 0.0f;
              #pragma unroll
              for (int c4 = 0; c4 < 4; c4++) {
                float4 lv = *(const float4*)&Lb[c4 * 4];
                s = fmaf(lp[c4*4+0], lv.x, s);
                s = fmaf(lp[c4*4+1], lv.y, s);
                s = fmaf(lp[c4*4+2], lv.z, s);
                s = fmaf(lp[c4*4+3], lv.w, s);
              }
              w[c] -= s;
            }
          }
          #pragma unroll
          for (int j = 0; j < 16; j++) {
            float s = w[j];
            const float* Ld = Wf + (b0k + j) * LDP + b0k;
            #pragma unroll
            for (int l = 0; l < 16; l++) {
              if (l < j) s = fmaf(-w[l], Ld[l], s);
            }
            w[j] = s * mdiag[b0k + j];
          }
          float4* wp = (float4*)(Wf + r * LDP + b0k);
          wp[0] = make_float4(w[0], w[1], w[2], w[3]);
          wp[1] = make_float4(w[4], w[5], w[6], w[7]);
          wp[2] = make_float4(w[8], w[9], w[10], w[11]);
          wp[3] = make_float4(w[12], w[13], w[14], w[15]);
          unsigned short hs[16]; float lo[16];
          #pragma unroll
          for (int u = 0; u < 16; u++) {
            hs[u] = f2bf(w[u]);
            lo[u] = w[u] - __uint_as_float(((unsigned)hs[u]) << 16);
          }
          uint4 h0, h1;
          h0.x = hs[0] | ((unsigned)hs[1] << 16);   h0.y = hs[2] | ((unsigned)hs[3] << 16);
          h0.z = hs[4] | ((unsigned)hs[5] << 16);   h0.w = hs[6] | ((unsigned)hs[7] << 16);
          h1.x = hs[8] | ((unsigned)hs[9] << 16);   h1.y = hs[10] | ((unsigned)hs[11] << 16);
          h1.z = hs[12] | ((unsigned)hs[13] << 16); h1.w = hs[14] | ((unsigned)hs[15] << 16);
          unsigned short* hr = Lhi + r * LDB + b0k;
          unsigned short* lr = Llo + r * LDB + b0k;
          *(uint4*)(hr) = h0; *(uint4*)(hr + 8) = h1;
          *(uint4*)(lr) = pack8(lo); *(uint4*)(lr + 8) = pack8(lo + 8);
        }
      } else if (kb > 0) {
        // MFMA crew: panel kb-1 -> tiles (bi,bj), bj>=kb+1, excl diag kb+1.
        int cnt = 0;
        const int ko = bm1 + 8 * quad;   // valid only for quad<2
        #pragma unroll 1
        for (int bj = kb + 1; bj <= 7; bj++) {
          #pragma unroll 1
          for (int bi = bj; bi <= 7; bi++) {
            if (bi == kb + 1 && bj == kb + 1) continue;
            if (cnt % 13 == wave - 3) {
              bf16x8 ahi = {0,0,0,0,0,0,0,0}, alo = {0,0,0,0,0,0,0,0};
              bf16x8 bhi = {0,0,0,0,0,0,0,0}, blo = {0,0,0,0,0,0,0,0};
              if (quad < 2) {
                ahi = *(const bf16x8*)(Lhi + (16 * bi + m16) * LDB + ko);
                alo = *(const bf16x8*)(Llo + (16 * bi + m16) * LDB + ko);
                bhi = *(const bf16x8*)(Lhi + (16 * bj + m16) * LDB + ko);
                blo = *(const bf16x8*)(Llo + (16 * bj + m16) * LDB + ko);
              }
              f32x4 acc = (f32x4){0.0f, 0.0f, 0.0f, 0.0f};
              acc = __builtin_amdgcn_mfma_f32_16x16x32_bf16(ahi, bhi, acc, 0, 0, 0);
              acc = __builtin_amdgcn_mfma_f32_16x16x32_bf16(ahi, blo, acc, 0, 0, 0);
              acc = __builtin_amdgcn_mfma_f32_16x16x32_bf16(alo, bhi, acc, 0, 0, 0);
              #pragma unroll
              for (int reg = 0; reg < 4; reg++)
                Wf[(16 * bi + 4 * quad + reg) * LDP + 16 * bj + m16] -= acc[reg];
            }
            cnt++;
          }
        }
      }
      __syncthreads();
    }

    // ---- trinv: single barrier; uniform 2-chain worklist per wave ----
    {
      #pragma unroll 1
      for (int cc = 0; cc < 2; cc++) {
        const int J = cc ? (7 - grp) : grp;
        trinv_chain2(Wf, mdiag, J, pass, lane);
      }
      __syncthreads();
    }

    // ---- PHASE MC (single barrier): y=Mv + logdet; pack M^T -> Mtb ----
    {
      const int mrow = tid >> 3, kc = (tid & 7) * 16;
      float mtv[16];
      if (kc > mrow) {
        const float4* rp = (const float4*)(Wf + mrow * LDP + kc);
        float4 q0 = rp[0], q1 = rp[1], q2v = rp[2], q3 = rp[3];
        mtv[0]=q0.x; mtv[1]=q0.y; mtv[2]=q0.z; mtv[3]=q0.w;
        mtv[4]=q1.x; mtv[5]=q1.y; mtv[6]=q1.z; mtv[7]=q1.w;
        mtv[8]=q2v.x; mtv[9]=q2v.y; mtv[10]=q2v.z; mtv[11]=q2v.w;
        mtv[12]=q3.x; mtv[13]=q3.y; mtv[14]=q3.z; mtv[15]=q3.w;
      } else if (kc + 15 < mrow) {
        #pragma unroll
        for (int u = 0; u < 16; u++) mtv[u] = 0.0f;
      } else {
        #pragma unroll
        for (int u = 0; u < 16; u++) {
          const int k = kc + u;
          mtv[u] = (k > mrow) ? Wf[mrow * LDP + k]
                 : ((k == mrow) ? mdiag[mrow] : 0.0f);
        }
      }
      if (tid < DQ) {
        nllp -= __logf(mdiag[tid]);
        float s0 = 0.0f, s1 = 0.0f, s2 = 0.0f, s3 = 0.0f;
        int k = 0;
        for (; k + 3 < tid; k += 4) {
          s0 = fmaf(Wf[k * LDP + tid], vv[k], s0);
          s1 = fmaf(Wf[(k + 1) * LDP + tid], vv[k + 1], s1);
          s2 = fmaf(Wf[(k + 2) * LDP + tid], vv[k + 2], s2);
          s3 = fmaf(Wf[(k + 3) * LDP + tid], vv[k + 3], s3);
        }
        float s = fmaf(mdiag[tid], vv[tid], (s0 + s1) + (s2 + s3));
        for (; k < tid; k++) s = fmaf(Wf[k * LDP + tid], vv[k], s);
        yv[tid] = s;
      }
      unsigned short* mt = Mtb + mrow * LDB + kc;
      *(uint4*)(mt) = pack8(mtv);
      *(uint4*)(mt + 8) = pack8(mtv + 8);
      __syncthreads();
    }

    // ---- PHASE Pn (+fused A-build for step t+1): Sinv = M^T*M (lower);
    //      Pb = r2 I - r2^2 Sinv; m_post = z_t - r2*(Sinv v) -> mv;
    //      A(t+1) -> Ab2 ----
    {
      f32x4 acc[4];
      #pragma unroll
      for (int c = 0; c < 4; c++) acc[c] = (f32x4){0.0f, 0.0f, 0.0f, 0.0f};
      if (tid < DQ) nllp += 0.5f * yv[tid] * yv[tid];
      const int ctmax = rb - 4 * ch;
      if (ctmax >= 0) {
        for (int ks = (rb >> 1); ks < 4; ks++) {
          const int ko = 32 * ks + 8 * quad;
          bf16x8 a = *(const bf16x8*)(Mtb + (16 * rb + m16) * LDB + ko);
          #pragma unroll
          for (int ct = 0; ct < 4; ct++) {
            if (ct <= ctmax) {
              bf16x8 bb = *(const bf16x8*)(Mtb + (64 * ch + 16 * ct + m16) * LDB + ko);
              acc[ct] = __builtin_amdgcn_mfma_f32_16x16x32_bf16(a, bb, acc[ct], 0, 0, 0);
            }
          }
        }
      }
      const float nr22 = -r2 * r2;
      #pragma unroll
      for (int ct = 0; ct < 4; ct++) {
        if (ct <= ctmax) {
          const bool strict = (ct < ctmax);
          #pragma unroll
          for (int reg = 0; reg < 4; reg++) {
            const int rg = 16 * rb + 4 * quad + reg;
            const int cgl = 64 * ch + 16 * ct + m16;
            unsigned short hv = f2bf(nr22 * acc[ct][reg] + ((rg == cgl) ? r2 : 0.0f));
            Pb[rg * LDB + cgl] = hv;
            if (strict) Pb[cgl * LDB + rg] = hv;
          }
        }
      }
      if (tid < DQ) {
        const unsigned* mr = (const unsigned*)(Mtb + tid * LDB);
        float sa = 0.0f, sb = 0.0f;
        #pragma unroll 8
        for (int k2 = 0; k2 < 64; k2 += 2) {
          unsigned p0 = mr[k2], p1 = mr[k2 + 1];
          sa = fmaf(__uint_as_float(p0 << 16), yv[2 * k2], sa);
          sa = fmaf(__uint_as_float(p0 & 0xffff0000u), yv[2 * k2 + 1], sa);
          sb = fmaf(__uint_as_float(p1 << 16), yv[2 * k2 + 2], sb);
          sb = fmaf(__uint_as_float(p1 & 0xffff0000u), yv[2 * k2 + 3], sb);
        }
        mv[tid] = zt[tid] - r2 * (sa + sb);   // m_post = z - r2 * Sinv v
      }
      // ---- fused A-build for step t+1 (inputs only; independent) ----
      if (t < TQ - 1) {
        const float* mu_t = mu_seq + ((size_t)b * (TQ - 1) + t) * 4;
        const float* sg_t = sigma_seq + ((size_t)b * (TQ - 1) + t) * 16;
        const int unit = tid >> 2, q = tid & 3;
        const int r = unit >> 1, ss = unit & 1, tt = r >> 6, i = r & 63;
        float m0 = mu_t[0], m1 = mu_t[1], m2 = mu_t[2], m3 = mu_t[3];
        float dmx, dmy, c00, c01, c11;
        if (tt == 0 && ss == 0) {
          dmx = m0; dmy = m1;
          c00 = sg_t[0]; c01 = 0.5f * (sg_t[1] + sg_t[4]); c11 = sg_t[5];
        } else if (tt == 1 && ss == 1) {
          dmx = m2; dmy = m3;
          c00 = sg_t[10]; c01 = 0.5f * (sg_t[11] + sg_t[14]); c11 = sg_t[15];
        } else {
          dmx = 0.5f * (m0 + m2); dmy = 0.5f * (m1 + m3);
          float s00 = sg_t[0];
          float s02 = 0.5f * (sg_t[2] + sg_t[8]);
          float s22 = sg_t[10];
          float s01 = 0.5f * (sg_t[1] + sg_t[4]);
          float s03 = 0.5f * (sg_t[3] + sg_t[12]);
          float s21 = 0.5f * (sg_t[9] + sg_t[6]);
          float s23 = 0.5f * (sg_t[11] + sg_t[14]);
          float s11 = sg_t[5];
          float s13 = 0.5f * (sg_t[7] + sg_t[13]);
          float s33 = sg_t[15];
          c00 = 0.25f * (s00 + s02 + s02 + s22);
          c01 = 0.25f * (s01 + s03 + s21 + s23);
          c11 = 0.25f * (s11 + s13 + s13 + s33);
        }
        float D00 = 1.0001f + 2.0f * c00;
        float D01 = 2.0f * c01;
        float D11 = 1.0001f + 2.0f * c11;
        float det = D00 * D11 - D01 * D01;
        float dinv = 1.0f / det;
        float d00 = D11 * dinv, d01 = -D01 * dinv, d11 = D00 * dinv;
        float ldts = __logf(det);
        float cix = coords[2 * i], ciy = coords[2 * i + 1];
        const float* cj = coords + q * 32;
        float kv[16];
        float rsum = 0.0f;
        #pragma unroll
        for (int u = 0; u < 16; u++) {
          float dx = cix - cj[2 * u] - dmx;
          float dy = ciy - cj[2 * u + 1] - dmy;
          float qf = d00 * dx * dx + 2.0f * d01 * dx * dy + d11 * dy * dy;
          kv[u] = __expf(-0.5f * (qf + ldts));
          rsum += kv[u];
        }
        float rtot = rsum + __shfl_xor(rsum, 1);
        rtot += __shfl_xor(rtot, 2);
        float cv = (tt == 0) ? ((ss == 0) ? cpl00 : cpl01)
                             : ((ss == 0) ? cpl10 : cpl11);
        float norm = cv / fmaxf(rtot, 1e-6f);
        #pragma unroll
        for (int u = 0; u < 16; u++) kv[u] *= norm;
        if (ss == tt && ((i >> 4) == q)) kv[i & 15] += 1.0f - damping;
        unsigned short* arow = Ab2 + r * LDB + ss * 64 + q * 16;
        *(uint4*)(arow) = pack8(kv);
        *(uint4*)(arow + 8) = pack8(kv + 8);
      }
      __syncthreads();
    }
  }

  float total = block_reduce_sum(nllp, red);
  if (tid == 0)
    nll_out[b] = total + (float)TQ * 0.5f * (float)DQ * LOG2PI;
}

extern "C" __global__ void ide_finalize(const float* __restrict__ part,
                                        float* __restrict__ out) {
  if (threadIdx.x == 0) {
    float s = 0.0f;
    for (int i = 0; i < BQ; i++) s += part[i];
    out[0] = s * (1.0f / BQ);
  }
}

extern "C" void kernel_launch(void* const* d_in, const int* in_sizes, int n_in,
                              void* d_out, int out_size, void* d_ws, size_t ws_size,
                              hipStream_t stream) {
  (void)in_sizes; (void)n_in; (void)out_size; (void)ws_size;
  const float* z_seq        = (const float*)d_in[0];
  const float* site_lon     = (const float*)d_in[1];
  const float* site_lat     = (const float*)d_in[2];
  const float* mu_seq       = (const float*)d_in[3];
  const float* sigma_seq    = (const float*)d_in[4];
  const float* log_q        = (const float*)d_in[5];
  const float* log_r        = (const float*)d_in[6];
  const float* log_p0       = (const float*)d_in[7];
  const float* log_damp     = (const float*)d_in[8];
  const float* init_mean    = (const float*)d_in[9];
  const float* coupling_raw = (const float*)d_in[10];
  float* ws = (float*)d_ws;
  float* out = (float*)d_out;

  const size_t smem_bytes = (size_t)SMEM_FLOATS * sizeof(float);
  hipFuncSetAttribute((const void*)ide_kf_kernel,
                      hipFuncAttributeMaxDynamicSharedMemorySize,
                      (int)smem_bytes);

  hipLaunchKernelGGL(ide_kf_kernel, dim3(BQ), dim3(NTH), smem_bytes, stream,
                     z_seq, site_lon, site_lat, mu_seq, sigma_seq,
                     log_q, log_r, log_p0, log_damp, init_mean, coupling_raw,
                     ws);
  hipLaunchKernelGGL(ide_finalize, dim3(1), dim3(64), 0, stream, ws, out);
}

// Round 11
// 8890.287 us; speedup vs baseline: 1.1597x; 1.1597x over previous
//
#include <hip/hip_runtime.h>
#include <math.h>

// IDE state-space Kalman filter, MI355X (gfx950). Round 18:
// R16 STRUCTURE RESTORED (R17's right-looking merge re-violated the wave0
// rule: correction+TRSM+pack+MFMA+chol16 on one wave's chain -> +23%).
// HARD RULE: wave0's per-phase chain stays ~= chol16 only; merges move work
// to IDLE lanes exclusively. New in R18 (all idle-lane or local):
// - trinv step-1 (Linv_J column solves) hoisted into chol P1 phases: waves
//   4-7 (idle during TRSM) compute Linv_kb's 16 columns (diag kb factorized
//   last P2; writes diag-kb UPPER, read by nobody until trinv). Only J=7
//   keeps its in-chain solve. Removes a 16-step shfl solve from every
//   trinv chain's critical path.
// - MC y-GEMV 4-way accumulator split; Pn Sinv*v GEMV 2-way split.

#define SQ 64
#define DQ 128
#define TQ 128
#define BQ 16
#define LDP 132           // fp32 row stride
#define LDB 136           // bf16 row stride (16B-aligned rows, 2-way banks)
#define WFLOATS 17408     // W region: 69632 B (Tb + Ab2 bf16 when dead)
#define NTH 1024
#define LOG2PI 1.8378770664093454f

#define SMEM_FLOATS 35472

typedef __attribute__((ext_vector_type(8))) short bf16x8;
typedef __attribute__((ext_vector_type(4))) float f32x4;

__device__ __forceinline__ void lds_fence() {
  __asm__ volatile("s_waitcnt lgkmcnt(0)" ::: "memory");
}

__device__ __forceinline__ unsigned short f2bf(float f) {
  unsigned u = __float_as_uint(f);
  u += 0x7fffu + ((u >> 16) & 1u);
  return (unsigned short)(u >> 16);
}
__device__ __forceinline__ uint4 pack8(const float* v) {
  uint4 r;
  r.x = (unsigned)f2bf(v[0]) | ((unsigned)f2bf(v[1]) << 16);
  r.y = (unsigned)f2bf(v[2]) | ((unsigned)f2bf(v[3]) << 16);
  r.z = (unsigned)f2bf(v[4]) | ((unsigned)f2bf(v[5]) << 16);
  r.w = (unsigned)f2bf(v[6]) | ((unsigned)f2bf(v[7]) << 16);
  return r;
}

__device__ __forceinline__ float block_reduce_sum(float v, float* red) {
  #pragma unroll
  for (int off = 32; off > 0; off >>= 1) v += __shfl_down(v, off);
  const int tid = threadIdx.x;
  if ((tid & 63) == 0) red[tid >> 6] = v;
  __syncthreads();
  v = 0.0f;
  #pragma unroll
  for (int w = 0; w < NTH / 64; w++) v += red[w];
  __syncthreads();
  return v;
}

// 16x16 Cholesky, factor only (register/shfl resident on one wave).
__device__ __forceinline__ void chol16_f(float* __restrict__ Wf,
                                         float* __restrict__ mdiag,
                                         int b0, int lane) {
  float a[16];
  if (lane < 16) {
    const float4* rp = (const float4*)(Wf + (b0 + lane) * LDP + b0);
    float4 q0 = rp[0], q1 = rp[1], q2v = rp[2], q3 = rp[3];
    a[0]=q0.x; a[1]=q0.y; a[2]=q0.z; a[3]=q0.w;
    a[4]=q1.x; a[5]=q1.y; a[6]=q1.z; a[7]=q1.w;
    a[8]=q2v.x; a[9]=q2v.y; a[10]=q2v.z; a[11]=q2v.w;
    a[12]=q3.x; a[13]=q3.y; a[14]=q3.z; a[15]=q3.w;
  } else {
    #pragma unroll
    for (int i = 0; i < 16; i++) a[i] = 1.0f;
  }
  float myrinv = 1.0f;
  #pragma unroll
  for (int j = 0; j < 16; j++) {
    float dj = __shfl(a[j], j);
    float rinv = rsqrtf(dj);
    float lij = a[j] * rinv;
    a[j] = lij;
    if (lane == j) myrinv = rinv;
    #pragma unroll
    for (int k = j + 1; k < 16; k++) {
      float lkj = __shfl(lij, k);
      a[k] = fmaf(-lij, lkj, a[k]);
    }
  }
  if (lane < 16) {
    float4* rp = (float4*)(Wf + (b0 + lane) * LDP + b0);
    rp[0] = make_float4(a[0], a[1], a[2], a[3]);
    rp[1] = make_float4(a[4], a[5], a[6], a[7]);
    rp[2] = make_float4(a[8], a[9], a[10], a[11]);
    rp[3] = make_float4(a[12], a[13], a[14], a[15]);
    mdiag[b0 + lane] = myrinv;
  }
}

// One trinv chain: columns {4g+pass} of M(*,J). Linv_J columns are
// precomputed in the chol loop's P1 phases (do1 only for J=7).
__device__ __forceinline__ void trinv_chain2(float* __restrict__ Wf,
                                             const float* __restrict__ mdiag,
                                             int J, int pass, int lane,
                                             bool do1) {
  const int c16 = lane & 15;
  const int j16 = 4 * (lane >> 4) + pass;
  const int sh = lane & 48;
  if (do1) {
    float row[16];
    const float4* rp = (const float4*)(Wf + (J * 16 + c16) * LDP + J * 16);
    float4 a0 = rp[0], a1 = rp[1], a2 = rp[2], a3 = rp[3];
    row[0]=a0.x; row[1]=a0.y; row[2]=a0.z; row[3]=a0.w;
    row[4]=a1.x; row[5]=a1.y; row[6]=a1.z; row[7]=a1.w;
    row[8]=a2.x; row[9]=a2.y; row[10]=a2.z; row[11]=a2.w;
    row[12]=a3.x; row[13]=a3.y; row[14]=a3.z; row[15]=a3.w;
    float s = (c16 == j16) ? 1.0f : 0.0f;
    #pragma unroll
    for (int k = 0; k < 16; k++) {
      if (c16 == k) s *= mdiag[J * 16 + k];
      float sk = __shfl(s, sh | k);
      if (c16 > k) s = fmaf(-row[k], sk, s);
    }
    if (c16 > j16) Wf[(J * 16 + j16) * LDP + (J * 16 + c16)] = s;
    lds_fence();
  }
  const float md = mdiag[J * 16 + j16];
  const float* Mrow = Wf + (J * 16 + j16) * LDP + J * 16;
  #pragma unroll 1
  for (int I = J + 1; I < 8; I++) {
    const float* Lrow = Wf + (I * 16 + c16) * LDP + J * 16;
    float g = 0.0f;
    #pragma unroll
    for (int c4 = 0; c4 < 4; c4++) {
      float4 lv = *(const float4*)&Lrow[c4 * 4];
      float4 mq = *(const float4*)&Mrow[c4 * 4];
      float w0 = (c4*4+0 > j16) ? mq.x : ((c4*4+0 == j16) ? md : 0.0f);
      float w1 = (c4*4+1 > j16) ? mq.y : ((c4*4+1 == j16) ? md : 0.0f);
      float w2 = (c4*4+2 > j16) ? mq.z : ((c4*4+2 == j16) ? md : 0.0f);
      float w3 = (c4*4+3 > j16) ? mq.w : ((c4*4+3 == j16) ? md : 0.0f);
      g = fmaf(lv.x, w0, g); g = fmaf(lv.y, w1, g);
      g = fmaf(lv.z, w2, g); g = fmaf(lv.w, w3, g);
    }
    for (int K = J + 1; K < I; K++) {
      const float* LK = Lrow + (K - J) * 16;
      const float* MK = Wf + (J * 16 + j16) * LDP + K * 16;
      #pragma unroll
      for (int c4 = 0; c4 < 4; c4++) {
        float4 lv = *(const float4*)&LK[c4 * 4];
        float4 mq = *(const float4*)&MK[c4 * 4];
        g = fmaf(lv.x, mq.x, g); g = fmaf(lv.y, mq.y, g);
        g = fmaf(lv.z, mq.z, g); g = fmaf(lv.w, mq.w, g);
      }
    }
    float row2[16];
    {
      const float4* rp2 = (const float4*)(Wf + (I * 16 + c16) * LDP + I * 16);
      float4 a0 = rp2[0], a1 = rp2[1], a2 = rp2[2], a3 = rp2[3];
      row2[0]=a0.x; row2[1]=a0.y; row2[2]=a0.z; row2[3]=a0.w;
      row2[4]=a1.x; row2[5]=a1.y; row2[6]=a1.z; row2[7]=a1.w;
      row2[8]=a2.x; row2[9]=a2.y; row2[10]=a2.z; row2[11]=a2.w;
      row2[12]=a3.x; row2[13]=a3.y; row2[14]=a3.z; row2[15]=a3.w;
    }
    float sv = g;
    #pragma unroll
    for (int k = 0; k < 16; k++) {
      if (c16 == k) sv *= mdiag[I * 16 + k];
      float sk = __shfl(sv, sh | k);
      if (c16 > k) sv = fmaf(-row2[k], sk, sv);
    }
    Wf[(J * 16 + j16) * LDP + (I * 16 + c16)] = -sv;
    lds_fence();
  }
}

extern "C" __global__ __launch_bounds__(NTH, 4)
void ide_kf_kernel(const float* __restrict__ z_seq,
                   const float* __restrict__ site_lon,
                   const float* __restrict__ site_lat,
                   const float* __restrict__ mu_seq,
                   const float* __restrict__ sigma_seq,
                   const float* __restrict__ log_q,
                   const float* __restrict__ log_r,
                   const float* __restrict__ log_p0,
                   const float* __restrict__ log_damp,
                   const float* __restrict__ init_mean,
                   const float* __restrict__ coupling_raw,
                   float* __restrict__ ws) {
  extern __shared__ float smem[];
  float* Wf     = smem;                  // 17408 floats (fp32 chol space)
  float* B1f    = Wf + WFLOATS;          // 8704 floats (Mtb bf16 / Lhi)
  float* B2f    = B1f + 8704;            // 8704 floats (Pb bf16 / Llo)
  float* coords = B2f + 8704;            // 128
  float* mv     = coords + 128;          // 128 (posterior mean)
  float* vv     = mv + DQ;               // 128
  float* yv     = vv + DQ;               // 128
  float* mdiag  = yv + DQ;               // 128
  float* red    = mdiag + DQ;            // 16

  unsigned short* Tb  = (unsigned short*)Wf;            // bf16, stride LDB
  unsigned short* Ab2 = (unsigned short*)Wf + 17408;    // A bf16 (Wf upper)
  unsigned short* Mtb = (unsigned short*)B1f;           // M^T bf16
  unsigned short* Pb  = (unsigned short*)B2f;           // P bf16 (symmetric)
  unsigned short* Lhi = (unsigned short*)B1f;           // chol L hi (Mtb dead)
  unsigned short* Llo = (unsigned short*)B2f;           // chol L lo (Pb dead)

  const int tid = threadIdx.x;
  const int lane = tid & 63;
  const int wave = tid >> 6;
  const int rb = wave >> 1, ch = wave & 1;
  const int m16 = lane & 15, quad = lane >> 4;
  const int grp = wave >> 2, pass = wave & 3;
  const int b = blockIdx.x;
  float* nll_out = ws;

  const float r2 = __expf(2.0f * log_r[0]);
  const float q2 = __expf(2.0f * log_q[0]);
  const float p0sq = __expf(2.0f * log_p0[0]);
  const float damping = __expf(log_damp[0]);
  const float cpl00 = 1.0f + 0.25f * tanhf(coupling_raw[0]);
  const float cpl01 = 0.25f * tanhf(coupling_raw[1]);
  const float cpl10 = 0.25f * tanhf(coupling_raw[2]);
  const float cpl11 = 1.0f + 0.25f * tanhf(coupling_raw[3]);

  // ---- lon/lat projection ----
  float myLon = (tid < SQ) ? site_lon[tid] : 0.0f;
  float myLat = (tid < SQ) ? site_lat[tid] : 0.0f;
  float lat0 = block_reduce_sum(myLat, red) * (1.0f / 64.0f);
  float lon0 = block_reduce_sum(myLon, red) * (1.0f / 64.0f);
  if (tid < SQ) {
    const float km = 111.32f;
    float cs = cosf(lat0 * 0.017453292519943295f);
    coords[2 * tid]     = (myLon - lon0) * (km * cs);
    coords[2 * tid + 1] = (myLat - lat0) * km;
  }
  __syncthreads();
  float dsum = 0.0f, dcnt = 0.0f;
  for (int idx = tid; idx < SQ * SQ; idx += NTH) {
    int i = idx >> 6, j = idx & 63;
    float dx = coords[2 * i] - coords[2 * j];
    float dy = coords[2 * i + 1] - coords[2 * j + 1];
    float d = sqrtf(dx * dx + dy * dy + 1e-12f);
    dsum += d;
    if (d > 1e-6f) dcnt += 1.0f;
  }
  dsum = block_reduce_sum(dsum, red);
  dcnt = block_reduce_sum(dcnt, red);
  float scale = dsum / fmaxf(dcnt, 1.0f);
  float sdiv = 1.0f / fmaxf(scale, 1e-6f);
  if (tid < SQ) { coords[2 * tid] *= sdiv; coords[2 * tid + 1] *= sdiv; }

  // ---- init: Wf = (p0sq+r2) I, mv = init_mean ----
  for (int e = tid; e < WFLOATS / 4; e += NTH)
    ((float4*)Wf)[e] = make_float4(0.0f, 0.0f, 0.0f, 0.0f);
  for (int e = tid; e < 8704 / 4; e += NTH)
    ((float4*)B2f)[e] = make_float4(0.0f, 0.0f, 0.0f, 0.0f);
  __syncthreads();
  if (tid < DQ) {
    Wf[tid * LDP + tid] = p0sq + r2;
    mv[tid] = init_mean[tid];
  }
  __syncthreads();

  float nllp = 0.0f;

  #pragma unroll 1
  for (int t = 0; t < TQ; t++) {
    const float* zt = z_seq + ((size_t)b * TQ + t) * DQ;

    if (t > 0) {
      // ---- PHASE T: mfma T = A*P -> Tb (single barrier) ----
      {
        f32x4 acc[4];
        #pragma unroll
        for (int c = 0; c < 4; c++) acc[c] = (f32x4){0.0f, 0.0f, 0.0f, 0.0f};
        #pragma unroll
        for (int ks = 0; ks < 4; ks++) {
          const int ko = 32 * ks + 8 * quad;
          bf16x8 a = *(const bf16x8*)(Ab2 + (16 * rb + m16) * LDB + ko);
          #pragma unroll
          for (int ct = 0; ct < 4; ct++) {
            bf16x8 bb = *(const bf16x8*)(Pb + (64 * ch + 16 * ct + m16) * LDB + ko);
            acc[ct] = __builtin_amdgcn_mfma_f32_16x16x32_bf16(a, bb, acc[ct], 0, 0, 0);
          }
        }
        #pragma unroll
        for (int ct = 0; ct < 4; ct++)
          #pragma unroll
          for (int reg = 0; reg < 4; reg++)
            Tb[(16 * rb + 4 * quad + reg) * LDB + 64 * ch + 16 * ct + m16] =
                f2bf(acc[ct][reg]);
        __syncthreads();
      }

      // ---- PHASE P': part1: Sm MFMA + m-GEMV (idle waves 1,3);
      //      midbar; part2: fp32 Wf + wave0 chol16_f(0) + vv ----
      {
        const int ctmax = rb - 4 * ch;
        f32x4 acc[4];
        #pragma unroll
        for (int c = 0; c < 4; c++) acc[c] = (f32x4){0.0f, 0.0f, 0.0f, 0.0f};
        const bool gemv_wave = (wave == 1 || wave == 3);
        const int grow = (wave == 1) ? lane : 64 + lane;
        float newm = 0.0f;
        if (ctmax >= 0) {
          #pragma unroll
          for (int ks = 0; ks < 4; ks++) {
            const int ko = 32 * ks + 8 * quad;
            bf16x8 a = *(const bf16x8*)(Tb + (16 * rb + m16) * LDB + ko);
            #pragma unroll
            for (int ct = 0; ct < 4; ct++) {
              if (ct <= ctmax) {
                bf16x8 bb = *(const bf16x8*)(Ab2 + (64 * ch + 16 * ct + m16) * LDB + ko);
                acc[ct] = __builtin_amdgcn_mfma_f32_16x16x32_bf16(a, bb, acc[ct], 0, 0, 0);
              }
            }
          }
        } else if (gemv_wave) {
          const unsigned* ar = (const unsigned*)(Ab2 + grow * LDB);
          #pragma unroll 8
          for (int k2 = 0; k2 < 64; k2++) {
            unsigned p = ar[k2];
            newm = fmaf(__uint_as_float(p << 16), mv[2 * k2], newm);
            newm = fmaf(__uint_as_float(p & 0xffff0000u), mv[2 * k2 + 1], newm);
          }
        }
        __syncthreads();   // Tb/Ab2 reads done
        if (ctmax >= 0) {
          #pragma unroll
          for (int ct = 0; ct < 4; ct++) {
            if (ct <= ctmax) {
              #pragma unroll
              for (int reg = 0; reg < 4; reg++) {
                const int rg = 16 * rb + 4 * quad + reg;
                const int cgl = 64 * ch + 16 * ct + m16;
                Wf[rg * LDP + cgl] = acc[ct][reg] + ((rg == cgl) ? (q2 + r2) : 0.0f);
              }
            }
          }
        }
        if (gemv_wave) vv[grow] = zt[grow] - newm;
        if (wave == 0) {
          lds_fence();
          chol16_f(Wf, mdiag, 0, lane);
        }
        __syncthreads();
      }
    }

    if (t == 0) {
      // ---- K0 (t=0 only): wave0 chol diag0 ; vv ----
      if (tid < 64) {
        chol16_f(Wf, mdiag, 0, lane);
      } else if (tid < 192) {
        const int i = tid - 64;
        vv[i] = zt[i] - mv[i];
      }
      __syncthreads();
    }

    // ---- chol: LEFT-LOOKING, split-bf16 MFMA column updates ----
    #pragma unroll 1
    for (int kb = 0; kb < 7; kb++) {
      const int b0k = kb * 16, base = b0k + 16, nbelow = DQ - base;
      // P1: TRSM rows base..127 vs diag kb + pack hi/lo + zero next slot;
      //     waves 4-7 (idle): compute Linv_kb columns -> diag-kb upper.
      if (tid < nbelow) {
        const int r = base + tid;
        float* wr = Wf + r * LDP + b0k;
        float w[16];
        #pragma unroll
        for (int u4 = 0; u4 < 4; u4++) {
          float4 w4 = *(const float4*)&wr[u4 * 4];
          w[u4*4] = w4.x; w[u4*4+1] = w4.y; w[u4*4+2] = w4.z; w[u4*4+3] = w4.w;
        }
        #pragma unroll
        for (int j = 0; j < 16; j++) {
          float s = w[j];
          #pragma unroll
          for (int l = 0; l < 16; l++) {
            if (l < j) s = fmaf(-w[l], Wf[(b0k + j) * LDP + b0k + l], s);
          }
          w[j] = s * mdiag[b0k + j];
        }
        #pragma unroll
        for (int u4 = 0; u4 < 4; u4++)
          *(float4*)&wr[u4 * 4] =
              make_float4(w[u4*4], w[u4*4+1], w[u4*4+2], w[u4*4+3]);
        // split-bf16 pack: w = hi + lo
        unsigned short hs[16]; float lo[16];
        #pragma unroll
        for (int u = 0; u < 16; u++) {
          hs[u] = f2bf(w[u]);
          lo[u] = w[u] - __uint_as_float(((unsigned)hs[u]) << 16);
        }
        uint4 h0, h1;
        h0.x = hs[0] | ((unsigned)hs[1] << 16);   h0.y = hs[2] | ((unsigned)hs[3] << 16);
        h0.z = hs[4] | ((unsigned)hs[5] << 16);   h0.w = hs[6] | ((unsigned)hs[7] << 16);
        h1.x = hs[8] | ((unsigned)hs[9] << 16);   h1.y = hs[10] | ((unsigned)hs[11] << 16);
        h1.z = hs[12] | ((unsigned)hs[13] << 16); h1.w = hs[14] | ((unsigned)hs[15] << 16);
        unsigned short* hr = Lhi + r * LDB + b0k;
        unsigned short* lr = Llo + r * LDB + b0k;
        *(uint4*)(hr) = h0; *(uint4*)(hr + 8) = h1;
        *(uint4*)(lr) = pack8(lo); *(uint4*)(lr + 8) = pack8(lo + 8);
        // zero next panel's column slot (odd-K chunk overshoot reads zeros)
        const uint4 z4 = make_uint4(0u, 0u, 0u, 0u);
        *(uint4*)(hr + 16) = z4; *(uint4*)(hr + 24) = z4;
        *(uint4*)(lr + 16) = z4; *(uint4*)(lr + 24) = z4;
      } else if (wave >= 4 && wave <= 7) {
        // Linv_kb column solve (hoisted trinv step-1), pass = wave-4.
        const int c16 = lane & 15;
        const int j16 = 4 * (lane >> 4) + (wave - 4);
        const int sh = lane & 48;
        float row[16];
        const float4* rp = (const float4*)(Wf + (b0k + c16) * LDP + b0k);
        float4 a0 = rp[0], a1 = rp[1], a2 = rp[2], a3 = rp[3];
        row[0]=a0.x; row[1]=a0.y; row[2]=a0.z; row[3]=a0.w;
        row[4]=a1.x; row[5]=a1.y; row[6]=a1.z; row[7]=a1.w;
        row[8]=a2.x; row[9]=a2.y; row[10]=a2.z; row[11]=a2.w;
        row[12]=a3.x; row[13]=a3.y; row[14]=a3.z; row[15]=a3.w;
        float s = (c16 == j16) ? 1.0f : 0.0f;
        #pragma unroll
        for (int k = 0; k < 16; k++) {
          if (c16 == k) s *= mdiag[b0k + k];
          float sk = __shfl(s, sh | k);
          if (c16 > k) s = fmaf(-row[k], sk, s);
        }
        if (c16 > j16) Wf[(b0k + j16) * LDP + (b0k + c16)] = s;
      }
      __syncthreads();
      // P2: U(kb+1): one wave per tile (bi, kb+1); wave0 = diag + chol16
      if (wave <= 6 - kb) {
        const int bi = kb + 1 + wave;
        const int nch = (kb + 2) >> 1;   // ceil(16(kb+1)/32)
        f32x4 acc = (f32x4){0.0f, 0.0f, 0.0f, 0.0f};
        for (int c = 0; c < nch; c++) {
          const int ko = 32 * c + 8 * quad;
          bf16x8 ahi = *(const bf16x8*)(Lhi + (16 * bi + m16) * LDB + ko);
          bf16x8 alo = *(const bf16x8*)(Llo + (16 * bi + m16) * LDB + ko);
          bf16x8 bhi = *(const bf16x8*)(Lhi + (base + m16) * LDB + ko);
          bf16x8 blo = *(const bf16x8*)(Llo + (base + m16) * LDB + ko);
          acc = __builtin_amdgcn_mfma_f32_16x16x32_bf16(ahi, bhi, acc, 0, 0, 0);
          acc = __builtin_amdgcn_mfma_f32_16x16x32_bf16(ahi, blo, acc, 0, 0, 0);
          acc = __builtin_amdgcn_mfma_f32_16x16x32_bf16(alo, bhi, acc, 0, 0, 0);
        }
        #pragma unroll
        for (int reg = 0; reg < 4; reg++)
          Wf[(16 * bi + 4 * quad + reg) * LDP + base + m16] -= acc[reg];
        if (wave == 0) {
          lds_fence();
          chol16_f(Wf, mdiag, base, lane);
        }
      }
      __syncthreads();
    }

    // ---- trinv: single barrier; step-1 pre-hoisted except J=7 ----
    {
      trinv_chain2(Wf, mdiag, grp, pass, lane, false);
      trinv_chain2(Wf, mdiag, 7 - grp, pass, lane, grp == 0);
      __syncthreads();
    }

    // ---- PHASE MC (single barrier): y=Mv + logdet; pack M^T -> Mtb ----
    {
      const int mrow = tid >> 3, kc = (tid & 7) * 16;
      float mtv[16];
      if (kc > mrow) {
        const float4* rp = (const float4*)(Wf + mrow * LDP + kc);
        float4 q0 = rp[0], q1 = rp[1], q2v = rp[2], q3 = rp[3];
        mtv[0]=q0.x; mtv[1]=q0.y; mtv[2]=q0.z; mtv[3]=q0.w;
        mtv[4]=q1.x; mtv[5]=q1.y; mtv[6]=q1.z; mtv[7]=q1.w;
        mtv[8]=q2v.x; mtv[9]=q2v.y; mtv[10]=q2v.z; mtv[11]=q2v.w;
        mtv[12]=q3.x; mtv[13]=q3.y; mtv[14]=q3.z; mtv[15]=q3.w;
      } else if (kc + 15 < mrow) {
        #pragma unroll
        for (int u = 0; u < 16; u++) mtv[u] = 0.0f;
      } else {
        #pragma unroll
        for (int u = 0; u < 16; u++) {
          const int k = kc + u;
          mtv[u] = (k > mrow) ? Wf[mrow * LDP + k]
                 : ((k == mrow) ? mdiag[mrow] : 0.0f);
        }
      }
      if (tid < DQ) {
        nllp -= __logf(mdiag[tid]);
        float s0 = 0.0f, s1 = 0.0f, s2 = 0.0f, s3 = 0.0f;
        int k = 0;
        for (; k + 3 < tid; k += 4) {
          s0 = fmaf(Wf[k * LDP + tid], vv[k], s0);
          s1 = fmaf(Wf[(k + 1) * LDP + tid], vv[k + 1], s1);
          s2 = fmaf(Wf[(k + 2) * LDP + tid], vv[k + 2], s2);
          s3 = fmaf(Wf[(k + 3) * LDP + tid], vv[k + 3], s3);
        }
        float s = fmaf(mdiag[tid], vv[tid], (s0 + s1) + (s2 + s3));
        for (; k < tid; k++) s = fmaf(Wf[k * LDP + tid], vv[k], s);
        yv[tid] = s;
      }
      unsigned short* mt = Mtb + mrow * LDB + kc;
      *(uint4*)(mt) = pack8(mtv);
      *(uint4*)(mt + 8) = pack8(mtv + 8);
      __syncthreads();
    }

    // ---- PHASE Pn (+fused A-build for step t+1): Sinv = M^T*M (lower);
    //      Pb = r2 I - r2^2 Sinv; m_post = z_t - r2*(Sinv v) -> mv;
    //      A(t+1) -> Ab2 ----
    {
      f32x4 acc[4];
      #pragma unroll
      for (int c = 0; c < 4; c++) acc[c] = (f32x4){0.0f, 0.0f, 0.0f, 0.0f};
      if (tid < DQ) nllp += 0.5f * yv[tid] * yv[tid];
      const int ctmax = rb - 4 * ch;
      if (ctmax >= 0) {
        for (int ks = (rb >> 1); ks < 4; ks++) {
          const int ko = 32 * ks + 8 * quad;
          bf16x8 a = *(const bf16x8*)(Mtb + (16 * rb + m16) * LDB + ko);
          #pragma unroll
          for (int ct = 0; ct < 4; ct++) {
            if (ct <= ctmax) {
              bf16x8 bb = *(const bf16x8*)(Mtb + (64 * ch + 16 * ct + m16) * LDB + ko);
              acc[ct] = __builtin_amdgcn_mfma_f32_16x16x32_bf16(a, bb, acc[ct], 0, 0, 0);
            }
          }
        }
      }
      const float nr22 = -r2 * r2;
      #pragma unroll
      for (int ct = 0; ct < 4; ct++) {
        if (ct <= ctmax) {
          const bool strict = (ct < ctmax);
          #pragma unroll
          for (int reg = 0; reg < 4; reg++) {
            const int rg = 16 * rb + 4 * quad + reg;
            const int cgl = 64 * ch + 16 * ct + m16;
            unsigned short hv = f2bf(nr22 * acc[ct][reg] + ((rg == cgl) ? r2 : 0.0f));
            Pb[rg * LDB + cgl] = hv;
            if (strict) Pb[cgl * LDB + rg] = hv;
          }
        }
      }
      if (tid < DQ) {
        const unsigned* mr = (const unsigned*)(Mtb + tid * LDB);
        float sa = 0.0f, sb = 0.0f;
        #pragma unroll 8
        for (int k2 = 0; k2 < 64; k2 += 2) {
          unsigned p0 = mr[k2], p1 = mr[k2 + 1];
          sa = fmaf(__uint_as_float(p0 << 16), yv[2 * k2], sa);
          sa = fmaf(__uint_as_float(p0 & 0xffff0000u), yv[2 * k2 + 1], sa);
          sb = fmaf(__uint_as_float(p1 << 16), yv[2 * k2 + 2], sb);
          sb = fmaf(__uint_as_float(p1 & 0xffff0000u), yv[2 * k2 + 3], sb);
        }
        mv[tid] = zt[tid] - r2 * (sa + sb);   // m_post = z - r2 * Sinv v
      }
      // ---- fused A-build for step t+1 (inputs only; independent) ----
      if (t < TQ - 1) {
        const float* mu_t = mu_seq + ((size_t)b * (TQ - 1) + t) * 4;
        const float* sg_t = sigma_seq + ((size_t)b * (TQ - 1) + t) * 16;
        const int unit = tid >> 2, q = tid & 3;
        const int r = unit >> 1, ss = unit & 1, tt = r >> 6, i = r & 63;
        float m0 = mu_t[0], m1 = mu_t[1], m2 = mu_t[2], m3 = mu_t[3];
        float dmx, dmy, c00, c01, c11;
        if (tt == 0 && ss == 0) {
          dmx = m0; dmy = m1;
          c00 = sg_t[0]; c01 = 0.5f * (sg_t[1] + sg_t[4]); c11 = sg_t[5];
        } else if (tt == 1 && ss == 1) {
          dmx = m2; dmy = m3;
          c00 = sg_t[10]; c01 = 0.5f * (sg_t[11] + sg_t[14]); c11 = sg_t[15];
        } else {
          dmx = 0.5f * (m0 + m2); dmy = 0.5f * (m1 + m3);
          float s00 = sg_t[0];
          float s02 = 0.5f * (sg_t[2] + sg_t[8]);
          float s22 = sg_t[10];
          float s01 = 0.5f * (sg_t[1] + sg_t[4]);
          float s03 = 0.5f * (sg_t[3] + sg_t[12]);
          float s21 = 0.5f * (sg_t[9] + sg_t[6]);
          float s23 = 0.5f * (sg_t[11] + sg_t[14]);
          float s11 = sg_t[5];
          float s13 = 0.5f * (sg_t[7] + sg_t[13]);
          float s33 = sg_t[15];
          c00 = 0.25f * (s00 + s02 + s02 + s22);
          c01 = 0.25f * (s01 + s03 + s21 + s23);
          c11 = 0.25f * (s11 + s13 + s13 + s33);
        }
        float D00 = 1.0001f + 2.0f * c00;
        float D01 = 2.0f * c01;
        float D11 = 1.0001f + 2.0f * c11;
        float det = D00 * D11 - D01 * D01;
        float dinv = 1.0f / det;
        float d00 = D11 * dinv, d01 = -D01 * dinv, d11 = D00 * dinv;
        float ldts = __logf(det);
        float cix = coords[2 * i], ciy = coords[2 * i + 1];
        const float* cj = coords + q * 32;
        float kv[16];
        float rsum = 0.0f;
        #pragma unroll
        for (int u = 0; u < 16; u++) {
          float dx = cix - cj[2 * u] - dmx;
          float dy = ciy - cj[2 * u + 1] - dmy;
          float qf = d00 * dx * dx + 2.0f * d01 * dx * dy + d11 * dy * dy;
          kv[u] = __expf(-0.5f * (qf + ldts));
          rsum += kv[u];
        }
        float rtot = rsum + __shfl_xor(rsum, 1);
        rtot += __shfl_xor(rtot, 2);
        float cv = (tt == 0) ? ((ss == 0) ? cpl00 : cpl01)
                             : ((ss == 0) ? cpl10 : cpl11);
        float norm = cv / fmaxf(rtot, 1e-6f);
        #pragma unroll
        for (int u = 0; u < 16; u++) kv[u] *= norm;
        if (ss == tt && ((i >> 4) == q)) kv[i & 15] += 1.0f - damping;
        unsigned short* arow = Ab2 + r * LDB + ss * 64 + q * 16;
        *(uint4*)(arow) = pack8(kv);
        *(uint4*)(arow + 8) = pack8(kv + 8);
      }
      __syncthreads();
    }
  }

  float total = block_reduce_sum(nllp, red);
  if (tid == 0)
    nll_out[b] = total + (float)TQ * 0.5f * (float)DQ * LOG2PI;
}

extern "C" __global__ void ide_finalize(const float* __restrict__ part,
                                        float* __restrict__ out) {
  if (threadIdx.x == 0) {
    float s = 0.0f;
    for (int i = 0; i < BQ; i++) s += part[i];
    out[0] = s * (1.0f / BQ);
  }
}

extern "C" void kernel_launch(void* const* d_in, const int* in_sizes, int n_in,
                              void* d_out, int out_size, void* d_ws, size_t ws_size,
                              hipStream_t stream) {
  (void)in_sizes; (void)n_in; (void)out_size; (void)ws_size;
  const float* z_seq        = (const float*)d_in[0];
  const float* site_lon     = (const float*)d_in[1];
  const float* site_lat     = (const float*)d_in[2];
  const float* mu_seq       = (const float*)d_in[3];
  const float* sigma_seq    = (const float*)d_in[4];
  const float* log_q        = (const float*)d_in[5];
  const float* log_r        = (const float*)d_in[6];
  const float* log_p0       = (const float*)d_in[7];
  const float* log_damp     = (const float*)d_in[8];
  const float* init_mean    = (const float*)d_in[9];
  const float* coupling_raw = (const float*)d_in[10];
  float* ws = (float*)d_ws;
  float* out = (float*)d_out;

  const size_t smem_bytes = (size_t)SMEM_FLOATS * sizeof(float);
  hipFuncSetAttribute((const void*)ide_kf_kernel,
                      hipFuncAttributeMaxDynamicSharedMemorySize,
                      (int)smem_bytes);

  hipLaunchKernelGGL(ide_kf_kernel, dim3(BQ), dim3(NTH), smem_bytes, stream,
                     z_seq, site_lon, site_lat, mu_seq, sigma_seq,
                     log_q, log_r, log_p0, log_damp, init_mean, coupling_raw,
                     ws);
  hipLaunchKernelGGL(ide_finalize, dim3(1), dim3(64), 0, stream, ws, out);
}

// Round 12
// 7806.017 us; speedup vs baseline: 1.3208x; 1.1389x over previous
//
#include <hip/hip_runtime.h>
#include <math.h>

// IDE state-space Kalman filter, MI355X (gfx950). Round 19:
// R16 base (8354 us; MC/Pn loops untouched) + Linv hoist done right:
// - Linv_kb column solves moved to chol P2 (waves 8-11, idle there; diag kb
//   final since previous P2). P2's phase max (wave0 MFMA+chol16) hides the
//   solve -- R18 put it in P1 where it BECAME the max for late kb (+6%).
// - Payoff: trinv I-step applies Linv_I as a matmul with INDEPENDENT shfls
//   of g (R10 pattern) instead of a 16-step dependent substitution, for
//   I<7 (Linv_I hoisted). Only I=7 keeps substitution. Serial chains per
//   wave in trinv: ~9 -> ~2-3.
// - J=7 step-1 solve kept in grp0's second chain (Linv_7 needed by MC only).

#define SQ 64
#define DQ 128
#define TQ 128
#define BQ 16
#define LDP 132           // fp32 row stride
#define LDB 136           // bf16 row stride (16B-aligned rows, 2-way banks)
#define WFLOATS 17408     // W region: 69632 B (Tb + Ab2 bf16 when dead)
#define NTH 1024
#define LOG2PI 1.8378770664093454f

#define SMEM_FLOATS 35472

typedef __attribute__((ext_vector_type(8))) short bf16x8;
typedef __attribute__((ext_vector_type(4))) float f32x4;

__device__ __forceinline__ void lds_fence() {
  __asm__ volatile("s_waitcnt lgkmcnt(0)" ::: "memory");
}

__device__ __forceinline__ unsigned short f2bf(float f) {
  unsigned u = __float_as_uint(f);
  u += 0x7fffu + ((u >> 16) & 1u);
  return (unsigned short)(u >> 16);
}
__device__ __forceinline__ uint4 pack8(const float* v) {
  uint4 r;
  r.x = (unsigned)f2bf(v[0]) | ((unsigned)f2bf(v[1]) << 16);
  r.y = (unsigned)f2bf(v[2]) | ((unsigned)f2bf(v[3]) << 16);
  r.z = (unsigned)f2bf(v[4]) | ((unsigned)f2bf(v[5]) << 16);
  r.w = (unsigned)f2bf(v[6]) | ((unsigned)f2bf(v[7]) << 16);
  return r;
}

__device__ __forceinline__ float block_reduce_sum(float v, float* red) {
  #pragma unroll
  for (int off = 32; off > 0; off >>= 1) v += __shfl_down(v, off);
  const int tid = threadIdx.x;
  if ((tid & 63) == 0) red[tid >> 6] = v;
  __syncthreads();
  v = 0.0f;
  #pragma unroll
  for (int w = 0; w < NTH / 64; w++) v += red[w];
  __syncthreads();
  return v;
}

// 16x16 Cholesky, factor only (register/shfl resident on one wave).
__device__ __forceinline__ void chol16_f(float* __restrict__ Wf,
                                         float* __restrict__ mdiag,
                                         int b0, int lane) {
  float a[16];
  if (lane < 16) {
    const float4* rp = (const float4*)(Wf + (b0 + lane) * LDP + b0);
    float4 q0 = rp[0], q1 = rp[1], q2v = rp[2], q3 = rp[3];
    a[0]=q0.x; a[1]=q0.y; a[2]=q0.z; a[3]=q0.w;
    a[4]=q1.x; a[5]=q1.y; a[6]=q1.z; a[7]=q1.w;
    a[8]=q2v.x; a[9]=q2v.y; a[10]=q2v.z; a[11]=q2v.w;
    a[12]=q3.x; a[13]=q3.y; a[14]=q3.z; a[15]=q3.w;
  } else {
    #pragma unroll
    for (int i = 0; i < 16; i++) a[i] = 1.0f;
  }
  float myrinv = 1.0f;
  #pragma unroll
  for (int j = 0; j < 16; j++) {
    float dj = __shfl(a[j], j);
    float rinv = rsqrtf(dj);
    float lij = a[j] * rinv;
    a[j] = lij;
    if (lane == j) myrinv = rinv;
    #pragma unroll
    for (int k = j + 1; k < 16; k++) {
      float lkj = __shfl(lij, k);
      a[k] = fmaf(-lij, lkj, a[k]);
    }
  }
  if (lane < 16) {
    float4* rp = (float4*)(Wf + (b0 + lane) * LDP + b0);
    rp[0] = make_float4(a[0], a[1], a[2], a[3]);
    rp[1] = make_float4(a[4], a[5], a[6], a[7]);
    rp[2] = make_float4(a[8], a[9], a[10], a[11]);
    rp[3] = make_float4(a[12], a[13], a[14], a[15]);
    mdiag[b0 + lane] = myrinv;
  }
}

// One trinv chain: columns {4g+pass} of M(*,J). Linv_J (J=0..6) precomputed
// in chol P2 phases; do1 only for J=7 (consumed by MC). I<7 applies Linv_I
// via independent-shfl matmul; I=7 falls back to dependent substitution.
__device__ __forceinline__ void trinv_chain2(float* __restrict__ Wf,
                                             const float* __restrict__ mdiag,
                                             int J, int pass, int lane,
                                             bool do1) {
  const int c16 = lane & 15;
  const int j16 = 4 * (lane >> 4) + pass;
  const int sh = lane & 48;
  if (do1) {
    float row[16];
    const float4* rp = (const float4*)(Wf + (J * 16 + c16) * LDP + J * 16);
    float4 a0 = rp[0], a1 = rp[1], a2 = rp[2], a3 = rp[3];
    row[0]=a0.x; row[1]=a0.y; row[2]=a0.z; row[3]=a0.w;
    row[4]=a1.x; row[5]=a1.y; row[6]=a1.z; row[7]=a1.w;
    row[8]=a2.x; row[9]=a2.y; row[10]=a2.z; row[11]=a2.w;
    row[12]=a3.x; row[13]=a3.y; row[14]=a3.z; row[15]=a3.w;
    float s = (c16 == j16) ? 1.0f : 0.0f;
    #pragma unroll
    for (int k = 0; k < 16; k++) {
      if (c16 == k) s *= mdiag[J * 16 + k];
      float sk = __shfl(s, sh | k);
      if (c16 > k) s = fmaf(-row[k], sk, s);
    }
    if (c16 > j16) Wf[(J * 16 + j16) * LDP + (J * 16 + c16)] = s;
    lds_fence();
  }
  const float md = mdiag[J * 16 + j16];
  const float* Mrow = Wf + (J * 16 + j16) * LDP + J * 16;
  #pragma unroll 1
  for (int I = J + 1; I < 8; I++) {
    const float* Lrow = Wf + (I * 16 + c16) * LDP + J * 16;
    float g = 0.0f;
    // K = J: masked Linv_J read (hoisted upper + mdiag diagonal)
    #pragma unroll
    for (int c4 = 0; c4 < 4; c4++) {
      float4 lv = *(const float4*)&Lrow[c4 * 4];
      float4 mq = *(const float4*)&Mrow[c4 * 4];
      float w0 = (c4*4+0 > j16) ? mq.x : ((c4*4+0 == j16) ? md : 0.0f);
      float w1 = (c4*4+1 > j16) ? mq.y : ((c4*4+1 == j16) ? md : 0.0f);
      float w2 = (c4*4+2 > j16) ? mq.z : ((c4*4+2 == j16) ? md : 0.0f);
      float w3 = (c4*4+3 > j16) ? mq.w : ((c4*4+3 == j16) ? md : 0.0f);
      g = fmaf(lv.x, w0, g); g = fmaf(lv.y, w1, g);
      g = fmaf(lv.z, w2, g); g = fmaf(lv.w, w3, g);
    }
    for (int K = J + 1; K < I; K++) {
      const float* LK = Lrow + (K - J) * 16;
      const float* MK = Wf + (J * 16 + j16) * LDP + K * 16;
      #pragma unroll
      for (int c4 = 0; c4 < 4; c4++) {
        float4 lv = *(const float4*)&LK[c4 * 4];
        float4 mq = *(const float4*)&MK[c4 * 4];
        g = fmaf(lv.x, mq.x, g); g = fmaf(lv.y, mq.y, g);
        g = fmaf(lv.z, mq.z, g); g = fmaf(lv.w, mq.w, g);
      }
    }
    if (I < 7) {
      // apply hoisted Linv_I: independent shfls of original g (fast path)
      float s = mdiag[I * 16 + c16] * g;
      #pragma unroll
      for (int k = 0; k < 15; k++) {
        float gk = __shfl(g, sh | k);
        if (k < c16) {
          float u = Wf[(I * 16 + k) * LDP + I * 16 + c16];
          s = fmaf(u, gk, s);
        }
      }
      Wf[(J * 16 + j16) * LDP + (I * 16 + c16)] = -s;
    } else {
      // I = 7: Linv_7 unavailable; dependent forward substitution
      float row2[16];
      {
        const float4* rp2 = (const float4*)(Wf + (I * 16 + c16) * LDP + I * 16);
        float4 a0 = rp2[0], a1 = rp2[1], a2 = rp2[2], a3 = rp2[3];
        row2[0]=a0.x; row2[1]=a0.y; row2[2]=a0.z; row2[3]=a0.w;
        row2[4]=a1.x; row2[5]=a1.y; row2[6]=a1.z; row2[7]=a1.w;
        row2[8]=a2.x; row2[9]=a2.y; row2[10]=a2.z; row2[11]=a2.w;
        row2[12]=a3.x; row2[13]=a3.y; row2[14]=a3.z; row2[15]=a3.w;
      }
      float sv = g;
      #pragma unroll
      for (int k = 0; k < 16; k++) {
        if (c16 == k) sv *= mdiag[I * 16 + k];
        float sk = __shfl(sv, sh | k);
        if (c16 > k) sv = fmaf(-row2[k], sk, sv);
      }
      Wf[(J * 16 + j16) * LDP + (I * 16 + c16)] = -sv;
    }
    lds_fence();
  }
}

extern "C" __global__ __launch_bounds__(NTH, 4)
void ide_kf_kernel(const float* __restrict__ z_seq,
                   const float* __restrict__ site_lon,
                   const float* __restrict__ site_lat,
                   const float* __restrict__ mu_seq,
                   const float* __restrict__ sigma_seq,
                   const float* __restrict__ log_q,
                   const float* __restrict__ log_r,
                   const float* __restrict__ log_p0,
                   const float* __restrict__ log_damp,
                   const float* __restrict__ init_mean,
                   const float* __restrict__ coupling_raw,
                   float* __restrict__ ws) {
  extern __shared__ float smem[];
  float* Wf     = smem;                  // 17408 floats (fp32 chol space)
  float* B1f    = Wf + WFLOATS;          // 8704 floats (Mtb bf16 / Lhi)
  float* B2f    = B1f + 8704;            // 8704 floats (Pb bf16 / Llo)
  float* coords = B2f + 8704;            // 128
  float* mv     = coords + 128;          // 128 (posterior mean)
  float* vv     = mv + DQ;               // 128
  float* yv     = vv + DQ;               // 128
  float* mdiag  = yv + DQ;               // 128
  float* red    = mdiag + DQ;            // 16

  unsigned short* Tb  = (unsigned short*)Wf;            // bf16, stride LDB
  unsigned short* Ab2 = (unsigned short*)Wf + 17408;    // A bf16 (Wf upper)
  unsigned short* Mtb = (unsigned short*)B1f;           // M^T bf16
  unsigned short* Pb  = (unsigned short*)B2f;           // P bf16 (symmetric)
  unsigned short* Lhi = (unsigned short*)B1f;           // chol L hi (Mtb dead)
  unsigned short* Llo = (unsigned short*)B2f;           // chol L lo (Pb dead)

  const int tid = threadIdx.x;
  const int lane = tid & 63;
  const int wave = tid >> 6;
  const int rb = wave >> 1, ch = wave & 1;
  const int m16 = lane & 15, quad = lane >> 4;
  const int grp = wave >> 2, pass = wave & 3;
  const int b = blockIdx.x;
  float* nll_out = ws;

  const float r2 = __expf(2.0f * log_r[0]);
  const float q2 = __expf(2.0f * log_q[0]);
  const float p0sq = __expf(2.0f * log_p0[0]);
  const float damping = __expf(log_damp[0]);
  const float cpl00 = 1.0f + 0.25f * tanhf(coupling_raw[0]);
  const float cpl01 = 0.25f * tanhf(coupling_raw[1]);
  const float cpl10 = 0.25f * tanhf(coupling_raw[2]);
  const float cpl11 = 1.0f + 0.25f * tanhf(coupling_raw[3]);

  // ---- lon/lat projection ----
  float myLon = (tid < SQ) ? site_lon[tid] : 0.0f;
  float myLat = (tid < SQ) ? site_lat[tid] : 0.0f;
  float lat0 = block_reduce_sum(myLat, red) * (1.0f / 64.0f);
  float lon0 = block_reduce_sum(myLon, red) * (1.0f / 64.0f);
  if (tid < SQ) {
    const float km = 111.32f;
    float cs = cosf(lat0 * 0.017453292519943295f);
    coords[2 * tid]     = (myLon - lon0) * (km * cs);
    coords[2 * tid + 1] = (myLat - lat0) * km;
  }
  __syncthreads();
  float dsum = 0.0f, dcnt = 0.0f;
  for (int idx = tid; idx < SQ * SQ; idx += NTH) {
    int i = idx >> 6, j = idx & 63;
    float dx = coords[2 * i] - coords[2 * j];
    float dy = coords[2 * i + 1] - coords[2 * j + 1];
    float d = sqrtf(dx * dx + dy * dy + 1e-12f);
    dsum += d;
    if (d > 1e-6f) dcnt += 1.0f;
  }
  dsum = block_reduce_sum(dsum, red);
  dcnt = block_reduce_sum(dcnt, red);
  float scale = dsum / fmaxf(dcnt, 1.0f);
  float sdiv = 1.0f / fmaxf(scale, 1e-6f);
  if (tid < SQ) { coords[2 * tid] *= sdiv; coords[2 * tid + 1] *= sdiv; }

  // ---- init: Wf = (p0sq+r2) I, mv = init_mean ----
  for (int e = tid; e < WFLOATS / 4; e += NTH)
    ((float4*)Wf)[e] = make_float4(0.0f, 0.0f, 0.0f, 0.0f);
  for (int e = tid; e < 8704 / 4; e += NTH)
    ((float4*)B2f)[e] = make_float4(0.0f, 0.0f, 0.0f, 0.0f);
  __syncthreads();
  if (tid < DQ) {
    Wf[tid * LDP + tid] = p0sq + r2;
    mv[tid] = init_mean[tid];
  }
  __syncthreads();

  float nllp = 0.0f;

  #pragma unroll 1
  for (int t = 0; t < TQ; t++) {
    const float* zt = z_seq + ((size_t)b * TQ + t) * DQ;

    if (t > 0) {
      // ---- PHASE T: mfma T = A*P -> Tb (single barrier) ----
      {
        f32x4 acc[4];
        #pragma unroll
        for (int c = 0; c < 4; c++) acc[c] = (f32x4){0.0f, 0.0f, 0.0f, 0.0f};
        #pragma unroll
        for (int ks = 0; ks < 4; ks++) {
          const int ko = 32 * ks + 8 * quad;
          bf16x8 a = *(const bf16x8*)(Ab2 + (16 * rb + m16) * LDB + ko);
          #pragma unroll
          for (int ct = 0; ct < 4; ct++) {
            bf16x8 bb = *(const bf16x8*)(Pb + (64 * ch + 16 * ct + m16) * LDB + ko);
            acc[ct] = __builtin_amdgcn_mfma_f32_16x16x32_bf16(a, bb, acc[ct], 0, 0, 0);
          }
        }
        #pragma unroll
        for (int ct = 0; ct < 4; ct++)
          #pragma unroll
          for (int reg = 0; reg < 4; reg++)
            Tb[(16 * rb + 4 * quad + reg) * LDB + 64 * ch + 16 * ct + m16] =
                f2bf(acc[ct][reg]);
        __syncthreads();
      }

      // ---- PHASE P': part1: Sm MFMA + m-GEMV (idle waves 1,3);
      //      midbar; part2: fp32 Wf + wave0 chol16_f(0) + vv ----
      {
        const int ctmax = rb - 4 * ch;
        f32x4 acc[4];
        #pragma unroll
        for (int c = 0; c < 4; c++) acc[c] = (f32x4){0.0f, 0.0f, 0.0f, 0.0f};
        const bool gemv_wave = (wave == 1 || wave == 3);
        const int grow = (wave == 1) ? lane : 64 + lane;
        float newm = 0.0f;
        if (ctmax >= 0) {
          #pragma unroll
          for (int ks = 0; ks < 4; ks++) {
            const int ko = 32 * ks + 8 * quad;
            bf16x8 a = *(const bf16x8*)(Tb + (16 * rb + m16) * LDB + ko);
            #pragma unroll
            for (int ct = 0; ct < 4; ct++) {
              if (ct <= ctmax) {
                bf16x8 bb = *(const bf16x8*)(Ab2 + (64 * ch + 16 * ct + m16) * LDB + ko);
                acc[ct] = __builtin_amdgcn_mfma_f32_16x16x32_bf16(a, bb, acc[ct], 0, 0, 0);
              }
            }
          }
        } else if (gemv_wave) {
          const unsigned* ar = (const unsigned*)(Ab2 + grow * LDB);
          #pragma unroll 8
          for (int k2 = 0; k2 < 64; k2++) {
            unsigned p = ar[k2];
            newm = fmaf(__uint_as_float(p << 16), mv[2 * k2], newm);
            newm = fmaf(__uint_as_float(p & 0xffff0000u), mv[2 * k2 + 1], newm);
          }
        }
        __syncthreads();   // Tb/Ab2 reads done
        if (ctmax >= 0) {
          #pragma unroll
          for (int ct = 0; ct < 4; ct++) {
            if (ct <= ctmax) {
              #pragma unroll
              for (int reg = 0; reg < 4; reg++) {
                const int rg = 16 * rb + 4 * quad + reg;
                const int cgl = 64 * ch + 16 * ct + m16;
                Wf[rg * LDP + cgl] = acc[ct][reg] + ((rg == cgl) ? (q2 + r2) : 0.0f);
              }
            }
          }
        }
        if (gemv_wave) vv[grow] = zt[grow] - newm;
        if (wave == 0) {
          lds_fence();
          chol16_f(Wf, mdiag, 0, lane);
        }
        __syncthreads();
      }
    }

    if (t == 0) {
      // ---- K0 (t=0 only): wave0 chol diag0 ; vv ----
      if (tid < 64) {
        chol16_f(Wf, mdiag, 0, lane);
      } else if (tid < 192) {
        const int i = tid - 64;
        vv[i] = zt[i] - mv[i];
      }
      __syncthreads();
    }

    // ---- chol: LEFT-LOOKING, split-bf16 MFMA column updates ----
    #pragma unroll 1
    for (int kb = 0; kb < 7; kb++) {
      const int b0k = kb * 16, base = b0k + 16, nbelow = DQ - base;
      // P1: TRSM rows base..127 vs diag kb + pack hi/lo + zero next slot
      if (tid < nbelow) {
        const int r = base + tid;
        float* wr = Wf + r * LDP + b0k;
        float w[16];
        #pragma unroll
        for (int u4 = 0; u4 < 4; u4++) {
          float4 w4 = *(const float4*)&wr[u4 * 4];
          w[u4*4] = w4.x; w[u4*4+1] = w4.y; w[u4*4+2] = w4.z; w[u4*4+3] = w4.w;
        }
        #pragma unroll
        for (int j = 0; j < 16; j++) {
          float s = w[j];
          #pragma unroll
          for (int l = 0; l < 16; l++) {
            if (l < j) s = fmaf(-w[l], Wf[(b0k + j) * LDP + b0k + l], s);
          }
          w[j] = s * mdiag[b0k + j];
        }
        #pragma unroll
        for (int u4 = 0; u4 < 4; u4++)
          *(float4*)&wr[u4 * 4] =
              make_float4(w[u4*4], w[u4*4+1], w[u4*4+2], w[u4*4+3]);
        // split-bf16 pack: w = hi + lo
        unsigned short hs[16]; float lo[16];
        #pragma unroll
        for (int u = 0; u < 16; u++) {
          hs[u] = f2bf(w[u]);
          lo[u] = w[u] - __uint_as_float(((unsigned)hs[u]) << 16);
        }
        uint4 h0, h1;
        h0.x = hs[0] | ((unsigned)hs[1] << 16);   h0.y = hs[2] | ((unsigned)hs[3] << 16);
        h0.z = hs[4] | ((unsigned)hs[5] << 16);   h0.w = hs[6] | ((unsigned)hs[7] << 16);
        h1.x = hs[8] | ((unsigned)hs[9] << 16);   h1.y = hs[10] | ((unsigned)hs[11] << 16);
        h1.z = hs[12] | ((unsigned)hs[13] << 16); h1.w = hs[14] | ((unsigned)hs[15] << 16);
        unsigned short* hr = Lhi + r * LDB + b0k;
        unsigned short* lr = Llo + r * LDB + b0k;
        *(uint4*)(hr) = h0; *(uint4*)(hr + 8) = h1;
        *(uint4*)(lr) = pack8(lo); *(uint4*)(lr + 8) = pack8(lo + 8);
        // zero next panel's column slot (odd-K chunk overshoot reads zeros)
        const uint4 z4 = make_uint4(0u, 0u, 0u, 0u);
        *(uint4*)(hr + 16) = z4; *(uint4*)(hr + 24) = z4;
        *(uint4*)(lr + 16) = z4; *(uint4*)(lr + 24) = z4;
      }
      __syncthreads();
      // P2: U(kb+1) tiles; wave0 diag + chol16; waves 8-11: Linv_kb solve
      if (wave <= 6 - kb) {
        const int bi = kb + 1 + wave;
        const int nch = (kb + 2) >> 1;   // ceil(16(kb+1)/32)
        f32x4 acc = (f32x4){0.0f, 0.0f, 0.0f, 0.0f};
        for (int c = 0; c < nch; c++) {
          const int ko = 32 * c + 8 * quad;
          bf16x8 ahi = *(const bf16x8*)(Lhi + (16 * bi + m16) * LDB + ko);
          bf16x8 alo = *(const bf16x8*)(Llo + (16 * bi + m16) * LDB + ko);
          bf16x8 bhi = *(const bf16x8*)(Lhi + (base + m16) * LDB + ko);
          bf16x8 blo = *(const bf16x8*)(Llo + (base + m16) * LDB + ko);
          acc = __builtin_amdgcn_mfma_f32_16x16x32_bf16(ahi, bhi, acc, 0, 0, 0);
          acc = __builtin_amdgcn_mfma_f32_16x16x32_bf16(ahi, blo, acc, 0, 0, 0);
          acc = __builtin_amdgcn_mfma_f32_16x16x32_bf16(alo, bhi, acc, 0, 0, 0);
        }
        #pragma unroll
        for (int reg = 0; reg < 4; reg++)
          Wf[(16 * bi + 4 * quad + reg) * LDP + base + m16] -= acc[reg];
        if (wave == 0) {
          lds_fence();
          chol16_f(Wf, mdiag, base, lane);
        }
      } else if (wave >= 8 && wave <= 11) {
        // Linv_kb column solve (pass = wave-8) -> diag-kb upper.
        // Diag kb final since previous P2 (barrier-separated); writes
        // disjoint from all P2/P1 readers until trinv.
        const int c16 = lane & 15;
        const int j16s = 4 * (lane >> 4) + (wave - 8);
        const int sh = lane & 48;
        float row[16];
        const float4* rp = (const float4*)(Wf + (b0k + c16) * LDP + b0k);
        float4 a0 = rp[0], a1 = rp[1], a2 = rp[2], a3 = rp[3];
        row[0]=a0.x; row[1]=a0.y; row[2]=a0.z; row[3]=a0.w;
        row[4]=a1.x; row[5]=a1.y; row[6]=a1.z; row[7]=a1.w;
        row[8]=a2.x; row[9]=a2.y; row[10]=a2.z; row[11]=a2.w;
        row[12]=a3.x; row[13]=a3.y; row[14]=a3.z; row[15]=a3.w;
        float s = (c16 == j16s) ? 1.0f : 0.0f;
        #pragma unroll
        for (int k = 0; k < 16; k++) {
          if (c16 == k) s *= mdiag[b0k + k];
          float sk = __shfl(s, sh | k);
          if (c16 > k) s = fmaf(-row[k], sk, s);
        }
        if (c16 > j16s) Wf[(b0k + j16s) * LDP + (b0k + c16)] = s;
      }
      __syncthreads();
    }

    // ---- trinv: single barrier; Linv pre-hoisted (J=0..6); fast I-apply ----
    {
      #pragma unroll 1
      for (int cc = 0; cc < 2; cc++) {
        const int J = cc ? (7 - grp) : grp;
        trinv_chain2(Wf, mdiag, J, pass, lane, cc == 1 && grp == 0);
      }
      __syncthreads();
    }

    // ---- PHASE MC (single barrier): y=Mv + logdet; pack M^T -> Mtb ----
    {
      const int mrow = tid >> 3, kc = (tid & 7) * 16;
      float mtv[16];
      if (kc > mrow) {
        const float4* rp = (const float4*)(Wf + mrow * LDP + kc);
        float4 q0 = rp[0], q1 = rp[1], q2v = rp[2], q3 = rp[3];
        mtv[0]=q0.x; mtv[1]=q0.y; mtv[2]=q0.z; mtv[3]=q0.w;
        mtv[4]=q1.x; mtv[5]=q1.y; mtv[6]=q1.z; mtv[7]=q1.w;
        mtv[8]=q2v.x; mtv[9]=q2v.y; mtv[10]=q2v.z; mtv[11]=q2v.w;
        mtv[12]=q3.x; mtv[13]=q3.y; mtv[14]=q3.z; mtv[15]=q3.w;
      } else if (kc + 15 < mrow) {
        #pragma unroll
        for (int u = 0; u < 16; u++) mtv[u] = 0.0f;
      } else {
        #pragma unroll
        for (int u = 0; u < 16; u++) {
          const int k = kc + u;
          mtv[u] = (k > mrow) ? Wf[mrow * LDP + k]
                 : ((k == mrow) ? mdiag[mrow] : 0.0f);
        }
      }
      if (tid < DQ) {
        nllp -= __logf(mdiag[tid]);
        float s = mdiag[tid] * vv[tid];
        for (int k = 0; k < tid; k++) s = fmaf(Wf[k * LDP + tid], vv[k], s);
        yv[tid] = s;
      }
      unsigned short* mt = Mtb + mrow * LDB + kc;
      *(uint4*)(mt) = pack8(mtv);
      *(uint4*)(mt + 8) = pack8(mtv + 8);
      __syncthreads();
    }

    // ---- PHASE Pn (+fused A-build for step t+1): Sinv = M^T*M (lower);
    //      Pb = r2 I - r2^2 Sinv; m_post = z_t - r2*(Sinv v) -> mv;
    //      A(t+1) -> Ab2 ----
    {
      f32x4 acc[4];
      #pragma unroll
      for (int c = 0; c < 4; c++) acc[c] = (f32x4){0.0f, 0.0f, 0.0f, 0.0f};
      if (tid < DQ) nllp += 0.5f * yv[tid] * yv[tid];
      const int ctmax = rb - 4 * ch;
      if (ctmax >= 0) {
        for (int ks = (rb >> 1); ks < 4; ks++) {
          const int ko = 32 * ks + 8 * quad;
          bf16x8 a = *(const bf16x8*)(Mtb + (16 * rb + m16) * LDB + ko);
          #pragma unroll
          for (int ct = 0; ct < 4; ct++) {
            if (ct <= ctmax) {
              bf16x8 bb = *(const bf16x8*)(Mtb + (64 * ch + 16 * ct + m16) * LDB + ko);
              acc[ct] = __builtin_amdgcn_mfma_f32_16x16x32_bf16(a, bb, acc[ct], 0, 0, 0);
            }
          }
        }
      }
      const float nr22 = -r2 * r2;
      #pragma unroll
      for (int ct = 0; ct < 4; ct++) {
        if (ct <= ctmax) {
          const bool strict = (ct < ctmax);
          #pragma unroll
          for (int reg = 0; reg < 4; reg++) {
            const int rg = 16 * rb + 4 * quad + reg;
            const int cgl = 64 * ch + 16 * ct + m16;
            unsigned short hv = f2bf(nr22 * acc[ct][reg] + ((rg == cgl) ? r2 : 0.0f));
            Pb[rg * LDB + cgl] = hv;
            if (strict) Pb[cgl * LDB + rg] = hv;
          }
        }
      }
      if (tid < DQ) {
        const unsigned* mr = (const unsigned*)(Mtb + tid * LDB);
        float s = 0.0f;
        #pragma unroll 8
        for (int k2 = 0; k2 < 64; k2++) {
          unsigned p = mr[k2];
          s = fmaf(__uint_as_float(p << 16), yv[2 * k2], s);
          s = fmaf(__uint_as_float(p & 0xffff0000u), yv[2 * k2 + 1], s);
        }
        mv[tid] = zt[tid] - r2 * s;   // m_post = z - r2 * Sinv v
      }
      // ---- fused A-build for step t+1 (inputs only; independent) ----
      if (t < TQ - 1) {
        const float* mu_t = mu_seq + ((size_t)b * (TQ - 1) + t) * 4;
        const float* sg_t = sigma_seq + ((size_t)b * (TQ - 1) + t) * 16;
        const int unit = tid >> 2, q = tid & 3;
        const int r = unit >> 1, ss = unit & 1, tt = r >> 6, i = r & 63;
        float m0 = mu_t[0], m1 = mu_t[1], m2 = mu_t[2], m3 = mu_t[3];
        float dmx, dmy, c00, c01, c11;
        if (tt == 0 && ss == 0) {
          dmx = m0; dmy = m1;
          c00 = sg_t[0]; c01 = 0.5f * (sg_t[1] + sg_t[4]); c11 = sg_t[5];
        } else if (tt == 1 && ss == 1) {
          dmx = m2; dmy = m3;
          c00 = sg_t[10]; c01 = 0.5f * (sg_t[11] + sg_t[14]); c11 = sg_t[15];
        } else {
          dmx = 0.5f * (m0 + m2); dmy = 0.5f * (m1 + m3);
          float s00 = sg_t[0];
          float s02 = 0.5f * (sg_t[2] + sg_t[8]);
          float s22 = sg_t[10];
          float s01 = 0.5f * (sg_t[1] + sg_t[4]);
          float s03 = 0.5f * (sg_t[3] + sg_t[12]);
          float s21 = 0.5f * (sg_t[9] + sg_t[6]);
          float s23 = 0.5f * (sg_t[11] + sg_t[14]);
          float s11 = sg_t[5];
          float s13 = 0.5f * (sg_t[7] + sg_t[13]);
          float s33 = sg_t[15];
          c00 = 0.25f * (s00 + s02 + s02 + s22);
          c01 = 0.25f * (s01 + s03 + s21 + s23);
          c11 = 0.25f * (s11 + s13 + s13 + s33);
        }
        float D00 = 1.0001f + 2.0f * c00;
        float D01 = 2.0f * c01;
        float D11 = 1.0001f + 2.0f * c11;
        float det = D00 * D11 - D01 * D01;
        float dinv = 1.0f / det;
        float d00 = D11 * dinv, d01 = -D01 * dinv, d11 = D00 * dinv;
        float ldts = __logf(det);
        float cix = coords[2 * i], ciy = coords[2 * i + 1];
        const float* cj = coords + q * 32;
        float kv[16];
        float rsum = 0.0f;
        #pragma unroll
        for (int u = 0; u < 16; u++) {
          float dx = cix - cj[2 * u] - dmx;
          float dy = ciy - cj[2 * u + 1] - dmy;
          float qf = d00 * dx * dx + 2.0f * d01 * dx * dy + d11 * dy * dy;
          kv[u] = __expf(-0.5f * (qf + ldts));
          rsum += kv[u];
        }
        float rtot = rsum + __shfl_xor(rsum, 1);
        rtot += __shfl_xor(rtot, 2);
        float cv = (tt == 0) ? ((ss == 0) ? cpl00 : cpl01)
                             : ((ss == 0) ? cpl10 : cpl11);
        float norm = cv / fmaxf(rtot, 1e-6f);
        #pragma unroll
        for (int u = 0; u < 16; u++) kv[u] *= norm;
        if (ss == tt && ((i >> 4) == q)) kv[i & 15] += 1.0f - damping;
        unsigned short* arow = Ab2 + r * LDB + ss * 64 + q * 16;
        *(uint4*)(arow) = pack8(kv);
        *(uint4*)(arow + 8) = pack8(kv + 8);
      }
      __syncthreads();
    }
  }

  float total = block_reduce_sum(nllp, red);
  if (tid == 0)
    nll_out[b] = total + (float)TQ * 0.5f * (float)DQ * LOG2PI;
}

extern "C" __global__ void ide_finalize(const float* __restrict__ part,
                                        float* __restrict__ out) {
  if (threadIdx.x == 0) {
    float s = 0.0f;
    for (int i = 0; i < BQ; i++) s += part[i];
    out[0] = s * (1.0f / BQ);
  }
}

extern "C" void kernel_launch(void* const* d_in, const int* in_sizes, int n_in,
                              void* d_out, int out_size, void* d_ws, size_t ws_size,
                              hipStream_t stream) {
  (void)in_sizes; (void)n_in; (void)out_size; (void)ws_size;
  const float* z_seq        = (const float*)d_in[0];
  const float* site_lon     = (const float*)d_in[1];
  const float* site_lat     = (const float*)d_in[2];
  const float* mu_seq       = (const float*)d_in[3];
  const float* sigma_seq    = (const float*)d_in[4];
  const float* log_q        = (const float*)d_in[5];
  const float* log_r        = (const float*)d_in[6];
  const float* log_p0       = (const float*)d_in[7];
  const float* log_damp     = (const float*)d_in[8];
  const float* init_mean    = (const float*)d_in[9];
  const float* coupling_raw = (const float*)d_in[10];
  float* ws = (float*)d_ws;
  float* out = (float*)d_out;

  const size_t smem_bytes = (size_t)SMEM_FLOATS * sizeof(float);
  hipFuncSetAttribute((const void*)ide_kf_kernel,
                      hipFuncAttributeMaxDynamicSharedMemorySize,
                      (int)smem_bytes);

  hipLaunchKernelGGL(ide_kf_kernel, dim3(BQ), dim3(NTH), smem_bytes, stream,
                     z_seq, site_lon, site_lat, mu_seq, sigma_seq,
                     log_q, log_r, log_p0, log_damp, init_mean, coupling_raw,
                     ws);
  hipLaunchKernelGGL(ide_finalize, dim3(1), dim3(64), 0, stream, ws, out);
}